// Round 6
// baseline (1440.764 us; speedup 1.0000x reference)
//
#include <hip/hip_runtime.h>

typedef unsigned short u16;
typedef unsigned int u32;
typedef __attribute__((ext_vector_type(8))) short short8;
typedef __attribute__((ext_vector_type(4))) float floatx4;

__device__ __forceinline__ float bf2f(u16 u) {
    union { unsigned int i; float f; } v; v.i = ((unsigned int)u) << 16; return v.f;
}
__device__ __forceinline__ u16 f2bf(float f) {
    union { float f; unsigned int i; } v; v.f = f;
    unsigned int i = v.i + 0x7fffu + ((v.i >> 16) & 1u);  // RNE
    return (u16)(i >> 16);
}

// async global->LDS, 16B per lane; LDS dest must be wave-uniform base + lane*16
#define GLL(g, l) __builtin_amdgcn_global_load_lds( \
    (const __attribute__((address_space(1))) void*)(g), \
    (__attribute__((address_space(3))) void*)(l), 16, 0, 0)

#define WAITVM(n) asm volatile("s_waitcnt vmcnt(" #n ")" ::: "memory")
#define SBAR() __builtin_amdgcn_sched_barrier(0)

// Ha halo tensor: [b][f_idx 0..65][t_idx 0..513 (pad 514)][ci 0..31] bf16
#define HA_BSTRIDE 1085568  // 66*514*32

// ---------------- dtype sniffer: flag=1 means inputs are float32 ----------------
__global__ __launch_bounds__(256) void sniff_k(const u16* __restrict__ x, int* __restrict__ flag) {
    __shared__ int red[4];
    int cnt = 0;
    for (int i = 0; i < 16; ++i) {
        u16 v = x[(threadIdx.x * 16 + i) * 2];
        int e = (v >> 7) & 0xFF;
        if (e >= 110 && e <= 135) cnt++;
    }
    #pragma unroll
    for (int off = 32; off; off >>= 1) cnt += __shfl_down(cnt, off);
    if ((threadIdx.x & 63) == 0) red[threadIdx.x >> 6] = cnt;
    __syncthreads();
    if (threadIdx.x == 0) {
        int tot = red[0] + red[1] + red[2] + red[3];
        *flag = (tot < 2048) ? 1 : 0;
    }
}

__device__ __forceinline__ float ldin(const void* p, size_t i, int isf32) {
    return isf32 ? ((const float*)p)[i] : bf2f(((const u16*)p)[i]);
}

// ---------------- canonicalize all params to f32 park (one launch) ----------------
struct CvtArgs {
    const void* src[19];
    int len[19];
    int off[19];
};
__global__ __launch_bounds__(256) void cvtall_k(CvtArgs a, float* __restrict__ dst,
                                                const int* __restrict__ flag) {
    int isf32 = *flag;
    int seg = blockIdx.y;
    int n = a.len[seg];
    const void* s = a.src[seg];
    float* d = dst + a.off[seg];
    for (int i = blockIdx.x * 256 + threadIdx.x; i < n; i += gridDim.x * 256)
        d[i] = ldin(s, i, isf32);
}

// ---------------- weight transpose: W[K][N] (dual dtype) -> Wt[N][K] bf16 ----------------
__global__ __launch_bounds__(256) void wtr_k(const void* __restrict__ W, int ldw, size_t wofs,
                                             u16* __restrict__ Wt, int ldt,
                                             const int* __restrict__ flag) {
    int isf32 = *flag;
    __shared__ u16 t[64][65];
    int k0 = blockIdx.x * 64, n0 = blockIdx.y * 64;
    int tid = threadIdx.x;
    #pragma unroll
    for (int i = 0; i < 16; ++i) {
        int kk = i * 4 + (tid >> 6), nn = tid & 63;
        t[kk][nn] = f2bf(ldin(W, wofs + (size_t)(k0 + kk) * ldw + n0 + nn, isf32));
    }
    __syncthreads();
    #pragma unroll
    for (int i = 0; i < 16; ++i) {
        int nn = i * 4 + (tid >> 6), kk = tid & 63;
        Wt[(size_t)(n0 + nn) * ldt + k0 + kk] = t[kk][nn];
    }
}

// ---------------- zero / guard fill ----------------
__global__ __launch_bounds__(256) void zero_k(float4* __restrict__ p, int n4) {
    float4 z = {0.f, 0.f, 0.f, 0.f};
    for (int i = blockIdx.x * 256 + threadIdx.x; i < n4; i += gridDim.x * 256) p[i] = z;
}
__global__ __launch_bounds__(256) void fill_k(float* __restrict__ p, int n) {
    int i = blockIdx.x * 256 + threadIdx.x;
    if (i < n) p[i] = 1.0e6f;
}

// ---------------- conv stem: 1->32, k3 s2 p1 -> X f32 NCHW; 4 co per thread ----------------
__global__ __launch_bounds__(256) void conv1_k(const void* __restrict__ x, const float* __restrict__ w,
                                               const float* __restrict__ bias, float* __restrict__ out,
                                               const int* __restrict__ flag) {
    int isf32 = *flag;
    int idx = blockIdx.x * 256 + threadIdx.x;   // 4,194,304 threads
    int t  = idx & 511;
    int f  = (idx >> 9) & 63;
    int cg = (idx >> 15) & 7;       // co = cg*4 + i
    int b  = idx >> 18;
    size_t xb = (size_t)b * 128 * 1024;

    float wr[4][9];
    #pragma unroll
    for (int i = 0; i < 4; ++i)
        #pragma unroll
        for (int k = 0; k < 9; ++k) wr[i][k] = w[(cg * 4 + i) * 9 + k];

    float acc[4];
    #pragma unroll
    for (int i = 0; i < 4; ++i) acc[i] = bias[cg * 4 + i];

    #pragma unroll
    for (int df = 0; df < 3; ++df) {
        int fi = 2 * f + df - 1;
        if (fi < 0 || fi >= 128) continue;       // wave-uniform branch
        size_t rowb = xb + (size_t)fi * 1024;
        float xv[3];
        #pragma unroll
        for (int dt = 0; dt < 3; ++dt) {
            int ti = 2 * t + dt - 1;
            float v = 0.f;
            if (ti >= 0 && ti < 1024) v = ldin(x, rowb + ti, isf32);
            xv[dt] = v;
        }
        #pragma unroll
        for (int i = 0; i < 4; ++i)
            #pragma unroll
            for (int dt = 0; dt < 3; ++dt)
                acc[i] = fmaf(wr[i][df * 3 + dt], xv[dt], acc[i]);
    }
    size_t obase = (((size_t)b * 32 + cg * 4) * 64 + f) * 512 + t;
    #pragma unroll
    for (int i = 0; i < 4; ++i) out[obase + (size_t)i * 64 * 512] = acc[i];
}

// ---------------- LN-over-f stats (dual-dtype input, NCHW) ----------------
__global__ __launch_bounds__(256) void stats_k(const void* __restrict__ X, int isbf,
                                               float* __restrict__ sm, float* __restrict__ sr) {
    int idx = blockIdx.x * 256 + threadIdx.x;  // 16*32*512
    int t  = idx & 511;
    int bc = idx >> 9;
    size_t base = (size_t)bc * 64 * 512 + t;
    float s = 0.f, s2 = 0.f;
    #pragma unroll 8
    for (int f = 0; f < 64; ++f) {
        float v = isbf ? bf2f(((const u16*)X)[base + f * 512]) : ((const float*)X)[base + f * 512];
        s += v; s2 += v * v;
    }
    float m  = s * (1.f / 64.f);
    float var = fmaxf(s2 * (1.f / 64.f) - m * m, 0.f);
    sm[idx] = m;
    sr[idx] = rsqrtf(var + 1e-5f);
}

// ---------------- apply LN+ReLU: NCHW (f32|bf16) -> Ha NHWC halo bf16 ----------------
__global__ __launch_bounds__(256) void apply_k(const void* __restrict__ in, int isbf,
                                               const float* __restrict__ sm, const float* __restrict__ sr,
                                               const float* __restrict__ g, const float* __restrict__ be,
                                               u16* __restrict__ Ha) {
    int f = blockIdx.x;
    int b = blockIdx.y;
    float gg = g[f], bb_ = be[f];
    for (int it = 0; it < 2; ++it) {
        int t = it * 256 + threadIdx.x;
        u32 pk[16];
        #pragma unroll
        for (int cp = 0; cp < 16; ++cp) {
            u32 w = 0;
            #pragma unroll
            for (int half = 0; half < 2; ++half) {
                int ci = cp * 2 + half;
                size_t xi = (((size_t)b * 32 + ci) * 64 + f) * 512 + t;
                float xv = isbf ? bf2f(((const u16*)in)[xi]) : ((const float*)in)[xi];
                int si = (b * 32 + ci) * 512 + t;
                float hv = fmaxf((xv - sm[si]) * sr[si] * gg + bb_, 0.f);
                w |= ((u32)f2bf(hv)) << (half * 16);
            }
            pk[cp] = w;
        }
        u32* orow = (u32*)(Ha + (size_t)b * HA_BSTRIDE + ((size_t)(f + 1) * 514 + (t + 1)) * 32);
        #pragma unroll
        for (int q = 0; q < 16; ++q) orow[q] = pk[q];
    }
}

// ---------------- conv32 k3 s1 p1 via MFMA: pipelined multi-t-tile version ----------------
#define CVL 4
__global__ __launch_bounds__(256) void convm_k(const u16* __restrict__ Ha, void* __restrict__ out,
                                               const float* __restrict__ w, const float* __restrict__ bias,
                                               const float* __restrict__ res) {
    __shared__ __align__(16) u16 act[2][1536 * 8];   // 2 x 24576 B
    int F0    = blockIdx.x * 16;
    int tbase = blockIdx.y * 64;
    int b     = blockIdx.z;
    const u16* Hb = Ha + (size_t)b * HA_BSTRIDE;
    int tid  = threadIdx.x;
    int lane = tid & 63;
    int wv   = tid >> 6;
    int quad = lane >> 4;
    int r    = lane & 15;
    int hasres = (res != nullptr);

    int ufp[6], utp[6], uq[6];
    #pragma unroll
    for (int it = 0; it < 6; ++it) {
        int u = it * 256 + tid;
        int u2 = (u < 1296) ? u : (u - 1296);
        int fp = u2 / 72;
        int rem = u2 - fp * 72;
        ufp[it] = fp; utp[it] = rem >> 2; uq[it] = rem & 3;
    }

    auto stage = [&](int tile, int bw) {
        int t00 = tbase + tile * 16;
        #pragma unroll
        for (int it = 0; it < 6; ++it) {
            int u = it * 256 + tid;
            GLL(Hb + ((size_t)(F0 + ufp[it]) * 514 + (t00 + utp[it])) * 32 + uq[it] * 8,
                &act[bw][u * 8]);
        }
    };

    short8 bfrag[3][3][2];
    #pragma unroll
    for (int df = 0; df < 3; ++df)
        #pragma unroll
        for (int dt = 0; dt < 3; ++dt)
            #pragma unroll
            for (int ct = 0; ct < 2; ++ct) {
                short8 v;
                #pragma unroll
                for (int j = 0; j < 8; ++j) {
                    int co = ct * 16 + r, ci = quad * 8 + j;
                    v[j] = (short)f2bf(w[(co * 32 + ci) * 9 + df * 3 + dt]);
                }
                bfrag[df][dt][ct] = v;
            }

    WAITVM(0);   // drain weight loads: vm FIFO starts clean
    SBAR();
    stage(0, 0);
    SBAR();

    int fb = wv * 4;   // this wave's local f base (4 f-rows per wave)
    #pragma unroll 1
    for (int i = 0; i < CVL; ++i) {
        if (i < CVL - 1) stage(i + 1, (i + 1) & 1);
        SBAR();
        if (i == 0)            { WAITVM(6); }
        else if (i < CVL - 1)  { if (hasres) WAITVM(22); else WAITVM(14); }
        else                   { if (hasres) WAITVM(16); else WAITVM(8); }
        SBAR();
        __builtin_amdgcn_s_barrier();   // raw barrier: all waves' stage_i done
        SBAR();

        const u16* ab = act[i & 1];
        floatx4 acc[4][2];
        #pragma unroll
        for (int ii = 0; ii < 4; ++ii)
            #pragma unroll
            for (int j = 0; j < 2; ++j)
                #pragma unroll
                for (int k = 0; k < 4; ++k) acc[ii][j][k] = 0.f;

        #pragma unroll
        for (int fh = 0; fh < 6; ++fh) {
            short8 af[3];
            #pragma unroll
            for (int dt = 0; dt < 3; ++dt)
                af[dt] = *(const short8*)&ab[((fb + fh) * 18 + (r + dt)) * 32 + quad * 8];
            #pragma unroll
            for (int df = 0; df < 3; ++df) {
                int rel = fh - df;
                if (rel < 0 || rel >= 4) continue;
                #pragma unroll
                for (int dt = 0; dt < 3; ++dt)
                    #pragma unroll
                    for (int ct = 0; ct < 2; ++ct)
                        acc[rel][ct] = __builtin_amdgcn_mfma_f32_16x16x32_bf16(
                            af[dt], bfrag[df][dt][ct], acc[rel][ct], 0, 0, 0);
            }
        }

        int t0 = tbase + i * 16;
        int tt = t0 + quad * 4;
        #pragma unroll
        for (int rel = 0; rel < 4; ++rel)
            #pragma unroll
            for (int ct = 0; ct < 2; ++ct) {
                int f  = F0 + fb + rel;
                int co = ct * 16 + r;
                size_t base = (((size_t)b * 32 + co) * 64 + f) * 512 + tt;
                float bs = bias[co];
                if (hasres) {
                    float4 rv = *(const float4*)(res + base);
                    float4 o;
                    o.x = acc[rel][ct][0] + bs + rv.x;
                    o.y = acc[rel][ct][1] + bs + rv.y;
                    o.z = acc[rel][ct][2] + bs + rv.z;
                    o.w = acc[rel][ct][3] + bs + rv.w;
                    *(float4*)((float*)out + base) = o;
                } else {
                    ushort4 o;
                    o.x = f2bf(acc[rel][ct][0] + bs);
                    o.y = f2bf(acc[rel][ct][1] + bs);
                    o.z = f2bf(acc[rel][ct][2] + bs);
                    o.w = f2bf(acc[rel][ct][3] + bs);
                    *(ushort4*)((u16*)out + base) = o;
                }
            }
        SBAR();
        __builtin_amdgcn_s_barrier();   // all waves done reading buf[i&1] before reuse
        SBAR();
    }
}

// ---------------- transpose X (b,c,f,t) f32 -> A[(t*16+b)][(c*64+f)] bf16 ----------------
__global__ __launch_bounds__(256) void transpose_k(const float* __restrict__ X, u16* __restrict__ A) {
    __shared__ float tile[64][65];
    int t0 = blockIdx.x * 64;
    int c  = blockIdx.y;
    int b  = blockIdx.z;
    const float* p = X + (((size_t)b * 32 + c) * 64) * 512 + t0;
    #pragma unroll
    for (int i = 0; i < 16; ++i) {
        int f = i * 4 + (threadIdx.x >> 6);
        int t = threadIdx.x & 63;
        tile[f][t] = p[(size_t)f * 512 + t];
    }
    __syncthreads();
    #pragma unroll
    for (int i = 0; i < 16; ++i) {
        int t = i * 4 + (threadIdx.x >> 6);
        int f = threadIdx.x & 63;
        A[((size_t)(t0 + t) * 16 + b) * 2048 + c * 64 + f] = f2bf(tile[f][t]);
    }
}

// ---------------- row layernorm, f32 in -> bf16 out ----------------
__global__ __launch_bounds__(256) void lnlast_k(const float* __restrict__ X, u16* __restrict__ Y,
                                                const float* __restrict__ g, const float* __restrict__ bt,
                                                int width) {
    int row = blockIdx.x;
    const float* p = X + (size_t)row * width;
    float s = 0.f, s2 = 0.f;
    for (int i = threadIdx.x; i < width; i += 256) { float v = p[i]; s += v; s2 += v * v; }
    #pragma unroll
    for (int off = 32; off; off >>= 1) { s += __shfl_down(s, off); s2 += __shfl_down(s2, off); }
    __shared__ float red[4][2];
    int wv = threadIdx.x >> 6;
    if ((threadIdx.x & 63) == 0) { red[wv][0] = s; red[wv][1] = s2; }
    __syncthreads();
    if (threadIdx.x == 0) {
        float a = 0.f, b2 = 0.f;
        for (int i = 0; i < 4; ++i) { a += red[i][0]; b2 += red[i][1]; }
        float m = a / width;
        float var = fmaxf(b2 / width - m * m, 0.f);
        red[0][0] = m; red[0][1] = rsqrtf(var + 1e-5f);
    }
    __syncthreads();
    float m = red[0][0], rs = red[0][1];
    u16* q = Y + (size_t)row * width;
    for (int i = threadIdx.x; i < width; i += 256)
        q[i] = f2bf((p[i] - m) * rs * g[i] + bt[i]);
}

// ---------------- MFMA GEMM: C = A @ Bt^T, 128x128, BK=64 (2 x 32-subtile) ----------------
// 2-buffer counted-vmcnt pipeline, two K=32 sub-steps fused per barrier pair
// (halves barrier/wait overhead vs R5's BK=32 x 3buf). Per stage: exactly 8 GLL
// per thread (A 4 + B 4, two subtiles); steady wait WAITVM(8) = previous stage
// complete, next stage in flight. Per-subtile LDS layout + XOR k-seg swizzle
// identical to the verified BK=32 version. Identity block mapping (R4: XCD
// swizzle quadrupled FETCH_SIZE on these L3-fit inputs).
__global__ __launch_bounds__(256) void gemm_bt(const u16* __restrict__ A, const u16* __restrict__ A2,
                                               int lda, const u16* __restrict__ Bt, int ldb,
                                               void* __restrict__ C, void* __restrict__ C2,
                                               int ldc, int nsplit,
                                               const float* __restrict__ bias, int relu, int K,
                                               int obf) {
    __shared__ __align__(16) u16 As[2][2][128 * 32];   // [buf][half][...]  32 KB
    __shared__ __align__(16) u16 Bs[2][2][128 * 32];   // 32 KB
    int tid  = threadIdx.x;
    int bm   = blockIdx.x * 128;
    int bn   = blockIdx.y * 128;

    const u16* Ab = A;
    void* Cb = C;
    int cn = bn;
    if (bn >= nsplit) { Ab = A2; Cb = C2; cn = bn - nsplit; }

    int lane = tid & 63;
    int wv   = tid >> 6;
    int quad = lane >> 4;
    int r    = lane & 15;
    int wm   = (wv >> 1) * 64;
    int wn   = (wv & 1) * 64;

    floatx4 acc[4][4];
    #pragma unroll
    for (int i = 0; i < 4; ++i)
        #pragma unroll
        for (int j = 0; j < 4; ++j)
            #pragma unroll
            for (int k = 0; k < 4; ++k) acc[i][j][k] = 0.f;

    int row0 = tid >> 2;
    int ks0  = ((tid & 3) ^ ((tid >> 3) & 3)) * 8;   // XOR swizzled k-seg
    const u16* Ab1 = Ab + (size_t)(bm + row0) * lda + ks0;
    const u16* Ab2 = Ab + (size_t)(bm + 64 + row0) * lda + ks0;
    const u16* Bb1 = Bt + (size_t)(bn + row0) * ldb + ks0;
    const u16* Bb2 = Bt + (size_t)(bn + 64 + row0) * ldb + ks0;

    auto stage = [&](int i2, int bw) {       // stage one K=64 tile (2 subtiles)
        int k0 = i2 * 64;
        GLL(Ab1 + k0,      &As[bw][0][tid * 8]);
        GLL(Ab2 + k0,      &As[bw][0][2048 + tid * 8]);
        GLL(Bb1 + k0,      &Bs[bw][0][tid * 8]);
        GLL(Bb2 + k0,      &Bs[bw][0][2048 + tid * 8]);
        GLL(Ab1 + k0 + 32, &As[bw][1][tid * 8]);
        GLL(Ab2 + k0 + 32, &As[bw][1][2048 + tid * 8]);
        GLL(Bb1 + k0 + 32, &Bs[bw][1][tid * 8]);
        GLL(Bb2 + k0 + 32, &Bs[bw][1][2048 + tid * 8]);
    };

    int nk2 = K >> 6;           // proj 32, SRU 16, FC1 16 — all >= 2
    WAITVM(0);                  // vm FIFO starts clean
    SBAR();
    stage(0, 0); stage(1, 1);
    SBAR();

    int col = (quad ^ ((r >> 1) & 3)) * 8;            // read-side un-swizzle
    int bc = 0;
    #pragma unroll 1
    for (int i = 0; i < nk2; ++i) {
        // wait for stage(i); stage(i+1) stays in flight (counted, no drain)
        if (i + 1 < nk2) { WAITVM(8); } else { WAITVM(0); }
        SBAR();
        __builtin_amdgcn_s_barrier();   // all waves' stage(i) complete
        SBAR();

        #pragma unroll
        for (int h = 0; h < 2; ++h) {
            const u16* as = As[bc][h];
            const u16* bs = Bs[bc][h];
            short8 af[4], bf[4];
            #pragma unroll
            for (int mi = 0; mi < 4; ++mi) af[mi] = *(const short8*)&as[(wm + mi * 16 + r) * 32 + col];
            #pragma unroll
            for (int ni = 0; ni < 4; ++ni) bf[ni] = *(const short8*)&bs[(wn + ni * 16 + r) * 32 + col];
            #pragma unroll
            for (int mi = 0; mi < 4; ++mi)
                #pragma unroll
                for (int ni = 0; ni < 4; ++ni)
                    acc[mi][ni] = __builtin_amdgcn_mfma_f32_16x16x32_bf16(af[mi], bf[ni], acc[mi][ni], 0, 0, 0);
        }

        SBAR();
        __builtin_amdgcn_s_barrier();   // all waves done reading buf bc
        SBAR();
        if (i + 2 < nk2) stage(i + 2, bc);   // reuse just-freed buffer
        bc ^= 1;
    }

    #pragma unroll
    for (int mi = 0; mi < 4; ++mi)
        #pragma unroll
        for (int ni = 0; ni < 4; ++ni) {
            int ccol = cn + wn + ni * 16 + r;
            float bsv = bias ? bias[ccol] : 0.f;
            #pragma unroll
            for (int reg = 0; reg < 4; ++reg) {
                int row = bm + wm + mi * 16 + quad * 4 + reg;
                float v = acc[mi][ni][reg] + bsv;
                if (relu) v = fmaxf(v, 0.f);
                if (obf) ((u16*)Cb)[(size_t)row * ldc + ccol] = f2bf(v);
                else     ((float*)Cb)[(size_t)row * ldc + ccol] = v;
            }
        }
}

// ---------------- SRU scan: 1 wave/block, 4-buffer counted-vmcnt pipeline ----------------
#define TC 256
__global__ __launch_bounds__(64) void scan_k(const u16* __restrict__ Uf, const u16* __restrict__ Ub,
                                             const float* __restrict__ Xp, float* __restrict__ Xn,
                                             float* __restrict__ cstate, const float* __restrict__ vv,
                                             const float* __restrict__ bb, int t0f, int t0b, int init) {
    __shared__ __align__(16) char lds[4][10240];
    int tid = threadIdx.x;
    int d   = blockIdx.x >> 7;
    int idx = blockIdx.x & 127;
    int b   = idx >> 3;
    int h0  = (idx & 7) * 64;
    int h   = h0 + tid;
    int gid = d * 8192 + idx * 64 + tid;

    float v0 = vv[(d * 2 + 0) * 512 + h];
    float v1 = vv[(d * 2 + 1) * 512 + h];
    float b0 = bb[(d * 2 + 0) * 512 + h];
    float b1 = bb[(d * 2 + 1) * 512 + h];
    const u16* U = d ? Ub : Uf;
    int t0 = d ? t0b : t0f;
    float* ob = Xn + (size_t)b * 1024 + d * 512 + h;
    float cc = init ? 0.f : cstate[gid];
    int tstp = d ? -16384 : 16384;

    const char* gp[10];
    int dlt[10];
    #pragma unroll
    for (int it = 0; it < 10; ++it) {
        int u = it * 64 + tid;
        int s = u / 40;
        int j = u - s * 40;
        int sl0 = d ? (TC - 1 - s) : s;
        if (j < 24) {
            int k = j >> 3, jj = j & 7;
            gp[it] = (const char*)(U + ((size_t)(sl0 * 16 + b) * 1536 + k * 512 + h0 + jj * 8));
            dlt[it] = d ? -786432 : 786432;        // 16 slots * 16 rows * 1536 * 2B
        } else {
            gp[it] = (const char*)(Xp + ((size_t)(t0 + sl0) * 16384 + (size_t)b * 1024 + d * 512 + h0 + (j - 24) * 4));
            dlt[it] = d ? -1048576 : 1048576;      // 16 * 16384 * 4B
        }
    }
    char* lbase = (char*)&lds[0][0] + tid * 16;
    auto stage = [&](int bw) {
        char* lb = lbase + bw * 10240;
        #pragma unroll
        for (int it = 0; it < 10; ++it) {
            GLL(gp[it], lb + it * 1024);
            gp[it] += dlt[it];
        }
    };

    asm volatile("s_waitcnt vmcnt(0)" ::: "memory");   // drain param loads: counts start at 0
    SBAR();
    stage(0);
    stage(1);
    stage(2);
    SBAR();

    #pragma unroll 1
    for (int tk = 0; tk < 16; ++tk) {
        switch (tk) {
            case 0:  WAITVM(20); break;   // s1+s2
            case 1:  WAITVM(36); break;   // s2+c0+s3
            case 14: WAITVM(42); break;   // c12+s15+c13
            case 15: WAITVM(32); break;   // c13+c14
            default: WAITVM(52); break;   // c+s+c+s
        }
        SBAR();
        const char* Bb = (const char*)&lds[0][0] + (size_t)(tk & 3) * 10240;
        float* op = ob + (size_t)(t0 + (d ? (TC - 1 - tk * 16) : tk * 16)) * 16384;
        #pragma unroll
        for (int s = 0; s < 16; ++s) {
            const char* sb = Bb + s * 640;
            float u0 = bf2f(*(const u16*)(sb + tid * 2));
            float fp = bf2f(*(const u16*)(sb + 128 + tid * 2)) + b0;
            float rp = bf2f(*(const u16*)(sb + 256 + tid * 2)) + b1;
            float xr = *(const float*)(sb + 384 + tid * 4);
            float f = 1.f / (1.f + __expf(-(fp + v0 * cc)));
            float r = 1.f / (1.f + __expf(-(rp + v1 * cc)));
            cc = f * cc + (1.f - f) * u0;
            float th = 1.f - 2.f / (__expf(2.f * cc) + 1.f);
            *op = r * th + (1.f - r) * xr;
            op += tstp;
        }
        SBAR();
        if (tk < 13) stage((tk + 3) & 3);
        SBAR();
    }
    cstate[gid] = cc;
}

// ---------------- classifier head: 2 rows/block, k split 4-way, shuffle+LDS reduce ------
__global__ __launch_bounds__(256) void cls2_k(const float* __restrict__ FC1, const float* __restrict__ W2,
                                              const float* __restrict__ b2, void* __restrict__ out,
                                              const int* __restrict__ flag) {
    int isf32 = *flag;
    int tid = threadIdx.x;
    int rh = tid >> 7;              // row within block (0..1)
    int ks = (tid >> 5) & 3;        // k-segment (0..3), 128 k each
    int v  = tid & 31;              // output class lane
    int row = blockIdx.x * 2 + rh;
    const float* p = FC1 + (size_t)row * 512 + ks * 128;
    const float* wp = W2 + (size_t)ks * 128 * 29;
    float acc = 0.f;
    #pragma unroll 4
    for (int k = 0; k < 128; ++k) {
        float wv = (v < 29) ? wp[k * 29 + v] : 0.f;
        acc = fmaf(p[k], wv, acc);
    }
    acc += __shfl_xor(acc, 32);     // merge ks pairs within wave
    __shared__ float red[2][2][32];
    if ((tid & 63) < 32) red[rh][(tid >> 6) & 1][v] = acc;
    __syncthreads();
    if ((tid & 127) < 32 && v < 29) {
        float s = red[rh][0][v] + red[rh][1][v] + b2[v];
        int t = row >> 4, b = row & 15;
        size_t oi = ((size_t)b * 512 + t) * 29 + v;
        if (isf32) ((float*)out)[oi] = s;
        else       ((u16*)out)[oi]   = f2bf(s);
    }
}

// ---------------- launch ----------------
extern "C" void kernel_launch(void* const* d_in, const int* in_sizes, int n_in,
                              void* d_out, int out_size, void* d_ws, size_t ws_size,
                              hipStream_t stream) {
    const void* x      = d_in[0];
    const void* proj_w = d_in[11];
    const void* sru_w  = d_in[12];
    const void* cls_w1 = d_in[19];

    float* ws = (float*)d_ws;
    const size_t O_X    = 0;
    const size_t O_C    = 16777216;
    const size_t O_HA   = 25165824;
    const size_t O_SM   = 33850368;
    const size_t O_SR   = 34112512;
    const size_t O_CST  = 34374656;
    const size_t O_PARK = 34391040;
    const size_t O_FLAG = 34483488;
    const size_t TOTAL  = 34483504;   // 131.55 MiB
    if (ws_size < TOTAL * sizeof(float)) {
        fill_k<<<(out_size + 255) / 256, 256, 0, stream>>>((float*)d_out, out_size);
        return;
    }

    float* X   = ws + O_X;
    u16*   C   = (u16*)(ws + O_C);
    u16*   HA  = (u16*)(ws + O_HA);
    float* SM  = ws + O_SM;
    float* SR  = ws + O_SR;
    float* CST = ws + O_CST;
    float* PK  = ws + O_PARK;
    int*   FLG = (int*)(ws + O_FLAG);

    u16*   Abf = (u16*)(ws + O_C);
    u16*   BtP = (u16*)(ws + 0);
    float* XP0 = ws + 25165824;
    u16*   XL  = (u16*)(ws + 0);
    float* XP1 = ws + 4194304;
    u16*   Uf  = (u16*)(ws + 12582912);
    u16*   Ub  = (u16*)(ws + 15728640);
    u16*   BtS = (u16*)(ws + 18874368);
    u16*   BtC = (u16*)(ws + O_SM);
    float* FC1 = ws + 12582912;

    float* p_cnn_w = PK + 0;      float* p_cnn_b = PK + 288;
    float* p_rw1   = PK + 320;    float* p_rb1   = PK + 27968;
    float* p_rw2   = PK + 28064;  float* p_rb2   = PK + 55712;
    float* p_l1g   = PK + 55808;  float* p_l1b   = PK + 56000;
    float* p_l2g   = PK + 56192;  float* p_l2b   = PK + 56384;
    float* p_sv    = PK + 56576;  float* p_sb    = PK + 62720;
    float* p_slng  = PK + 68864;  float* p_slnb  = PK + 71936;
    float* p_clng  = PK + 75008;  float* p_clnb  = PK + 76032;
    float* p_cb1   = PK + 77056;  float* p_cw2   = PK + 77568;
    float* p_cb2   = PK + 92416;

    sniff_k<<<1, 256, 0, stream>>>((const u16*)x, FLG);

    CvtArgs ca;
    const int srcidx[19] = {1,2,3,4,5,6,7,8,9,10,13,14,15,16,17,18,20,21,22};
    const int lens[19]   = {288,32,27648,96,27648,96,192,192,192,192,6144,6144,3072,3072,1024,1024,512,14848,29};
    const int offs[19]   = {0,288,320,27968,28064,55712,55808,56000,56192,56384,56576,62720,68864,71936,75008,76032,77056,77568,92416};
    for (int i = 0; i < 19; ++i) { ca.src[i] = d_in[srcidx[i]]; ca.len[i] = lens[i]; ca.off[i] = offs[i]; }
    cvtall_k<<<dim3(108, 19), 256, 0, stream>>>(ca, PK, FLG);

    zero_k<<<2048, 256, 0, stream>>>((float4*)HA, 2171136);
    conv1_k<<<16384, 256, 0, stream>>>(x, p_cnn_w, p_cnn_b, X, FLG);

    for (int i = 0; i < 3; ++i) {
        stats_k<<<1024, 256, 0, stream>>>(X, 0, SM, SR);
        apply_k<<<dim3(64, 16), 256, 0, stream>>>(X, 0, SM, SR, p_l1g + i * 64, p_l1b + i * 64, HA);
        convm_k<<<dim3(4, 8, 16), 256, 0, stream>>>(HA, C, p_rw1 + i * 9216, p_rb1 + i * 32, nullptr);
        stats_k<<<1024, 256, 0, stream>>>(C, 1, SM, SR);
        apply_k<<<dim3(64, 16), 256, 0, stream>>>(C, 1, SM, SR, p_l2g + i * 64, p_l2b + i * 64, HA);
        convm_k<<<dim3(4, 8, 16), 256, 0, stream>>>(HA, X, p_rw2 + i * 9216, p_rb2 + i * 32, X);
    }

    transpose_k<<<dim3(8, 32, 16), 256, 0, stream>>>(X, Abf);
    wtr_k<<<dim3(32, 16), 256, 0, stream>>>(proj_w, 1024, 0, BtP, 2048, FLG);
    gemm_bt<<<dim3(64, 8), 256, 0, stream>>>(Abf, Abf, 2048, BtP, 2048, XP0, XP0, 1024,
                                             1 << 30, nullptr, 0, 2048, 0);

    for (int l = 0; l < 3; ++l)
        wtr_k<<<dim3(16, 48), 256, 0, stream>>>(sru_w, 3072, (size_t)l * 3145728,
                                                BtS + (size_t)l * 3145728, 1024, FLG);
    wtr_k<<<dim3(16, 8), 256, 0, stream>>>(cls_w1, 512, 0, BtC, 1024, FLG);

    float* cur = XP0;
    float* nxt = XP1;
    for (int l = 0; l < 3; ++l) {
        lnlast_k<<<8192, 256, 0, stream>>>(cur, XL, p_slng + l * 1024, p_slnb + l * 1024, 1024);
        const u16* Btl = BtS + (size_t)l * 3145728;
        for (int j = 0; j < 2; ++j) {
            int t0f = j * TC;
            int t0b = (1 - j) * TC;
            gemm_bt<<<dim3(32, 24), 256, 0, stream>>>(XL + (size_t)t0f * 16 * 1024,
                                                      XL + (size_t)t0b * 16 * 1024, 1024,
                                                      Btl, 1024, Uf, Ub, 1536, 1536,
                                                      nullptr, 0, 1024, 1);
            scan_k<<<256, 64, 0, stream>>>(Uf, Ub, cur, nxt, CST,
                                           p_sv + l * 2048, p_sb + l * 2048, t0f, t0b, j == 0);
        }
        float* tmp = cur; cur = nxt; nxt = tmp;
    }

    lnlast_k<<<8192, 256, 0, stream>>>(cur, XL, p_clng, p_clnb, 1024);
    gemm_bt<<<dim3(64, 4), 256, 0, stream>>>(XL, XL, 1024, BtC, 1024, FC1, FC1, 512,
                                             1 << 30, p_cb1, 1, 1024, 0);
    cls2_k<<<4096, 256, 0, stream>>>(FC1, p_cw2, p_cb2, d_out, FLG);
}

// Round 7
// 1364.778 us; speedup vs baseline: 1.0557x; 1.0557x over previous
//
#include <hip/hip_runtime.h>

typedef unsigned short u16;
typedef unsigned int u32;
typedef __attribute__((ext_vector_type(8))) short short8;
typedef __attribute__((ext_vector_type(4))) float floatx4;

__device__ __forceinline__ float bf2f(u16 u) {
    union { unsigned int i; float f; } v; v.i = ((unsigned int)u) << 16; return v.f;
}
__device__ __forceinline__ u16 f2bf(float f) {
    union { float f; unsigned int i; } v; v.f = f;
    unsigned int i = v.i + 0x7fffu + ((v.i >> 16) & 1u);  // RNE
    return (u16)(i >> 16);
}

// async global->LDS, 16B per lane; LDS dest must be wave-uniform base + lane*16
#define GLL(g, l) __builtin_amdgcn_global_load_lds( \
    (const __attribute__((address_space(1))) void*)(g), \
    (__attribute__((address_space(3))) void*)(l), 16, 0, 0)

#define WAITVM(n) asm volatile("s_waitcnt vmcnt(" #n ")" ::: "memory")
#define WAITLG() asm volatile("s_waitcnt lgkmcnt(0)" ::: "memory")
#define SBAR() __builtin_amdgcn_sched_barrier(0)

// Ha halo tensor: [b][f_idx 0..65][t_idx 0..513 (pad 514)][ci 0..31] bf16
#define HA_BSTRIDE 1085568  // 66*514*32

// ---------------- dtype sniffer: flag=1 means inputs are float32 ----------------
__global__ __launch_bounds__(256) void sniff_k(const u16* __restrict__ x, int* __restrict__ flag) {
    __shared__ int red[4];
    int cnt = 0;
    for (int i = 0; i < 16; ++i) {
        u16 v = x[(threadIdx.x * 16 + i) * 2];
        int e = (v >> 7) & 0xFF;
        if (e >= 110 && e <= 135) cnt++;
    }
    #pragma unroll
    for (int off = 32; off; off >>= 1) cnt += __shfl_down(cnt, off);
    if ((threadIdx.x & 63) == 0) red[threadIdx.x >> 6] = cnt;
    __syncthreads();
    if (threadIdx.x == 0) {
        int tot = red[0] + red[1] + red[2] + red[3];
        *flag = (tot < 2048) ? 1 : 0;
    }
}

__device__ __forceinline__ float ldin(const void* p, size_t i, int isf32) {
    return isf32 ? ((const float*)p)[i] : bf2f(((const u16*)p)[i]);
}

// ---------------- canonicalize all params to f32 park (one launch) ----------------
struct CvtArgs {
    const void* src[19];
    int len[19];
    int off[19];
};
__global__ __launch_bounds__(256) void cvtall_k(CvtArgs a, float* __restrict__ dst,
                                                const int* __restrict__ flag) {
    int isf32 = *flag;
    int seg = blockIdx.y;
    int n = a.len[seg];
    const void* s = a.src[seg];
    float* d = dst + a.off[seg];
    for (int i = blockIdx.x * 256 + threadIdx.x; i < n; i += gridDim.x * 256)
        d[i] = ldin(s, i, isf32);
}

// ---------------- weight transpose: W[K][N] (dual dtype) -> Wt[N][K] bf16 ----------------
__global__ __launch_bounds__(256) void wtr_k(const void* __restrict__ W, int ldw, size_t wofs,
                                             u16* __restrict__ Wt, int ldt,
                                             const int* __restrict__ flag) {
    int isf32 = *flag;
    __shared__ u16 t[64][65];
    int k0 = blockIdx.x * 64, n0 = blockIdx.y * 64;
    int tid = threadIdx.x;
    #pragma unroll
    for (int i = 0; i < 16; ++i) {
        int kk = i * 4 + (tid >> 6), nn = tid & 63;
        t[kk][nn] = f2bf(ldin(W, wofs + (size_t)(k0 + kk) * ldw + n0 + nn, isf32));
    }
    __syncthreads();
    #pragma unroll
    for (int i = 0; i < 16; ++i) {
        int nn = i * 4 + (tid >> 6), kk = tid & 63;
        Wt[(size_t)(n0 + nn) * ldt + k0 + kk] = t[kk][nn];
    }
}

// ---------------- zero / guard fill ----------------
__global__ __launch_bounds__(256) void zero_k(float4* __restrict__ p, int n4) {
    float4 z = {0.f, 0.f, 0.f, 0.f};
    for (int i = blockIdx.x * 256 + threadIdx.x; i < n4; i += gridDim.x * 256) p[i] = z;
}
__global__ __launch_bounds__(256) void fill_k(float* __restrict__ p, int n) {
    int i = blockIdx.x * 256 + threadIdx.x;
    if (i < n) p[i] = 1.0e6f;
}

// ---------------- conv stem: 1->32, k3 s2 p1 -> X f32 NCHW; 4 co per thread ----------------
__global__ __launch_bounds__(256) void conv1_k(const void* __restrict__ x, const float* __restrict__ w,
                                               const float* __restrict__ bias, float* __restrict__ out,
                                               const int* __restrict__ flag) {
    int isf32 = *flag;
    int idx = blockIdx.x * 256 + threadIdx.x;   // 4,194,304 threads
    int t  = idx & 511;
    int f  = (idx >> 9) & 63;
    int cg = (idx >> 15) & 7;       // co = cg*4 + i
    int b  = idx >> 18;
    size_t xb = (size_t)b * 128 * 1024;

    float wr[4][9];
    #pragma unroll
    for (int i = 0; i < 4; ++i)
        #pragma unroll
        for (int k = 0; k < 9; ++k) wr[i][k] = w[(cg * 4 + i) * 9 + k];

    float acc[4];
    #pragma unroll
    for (int i = 0; i < 4; ++i) acc[i] = bias[cg * 4 + i];

    #pragma unroll
    for (int df = 0; df < 3; ++df) {
        int fi = 2 * f + df - 1;
        if (fi < 0 || fi >= 128) continue;       // wave-uniform branch
        size_t rowb = xb + (size_t)fi * 1024;
        float xv[3];
        #pragma unroll
        for (int dt = 0; dt < 3; ++dt) {
            int ti = 2 * t + dt - 1;
            float v = 0.f;
            if (ti >= 0 && ti < 1024) v = ldin(x, rowb + ti, isf32);
            xv[dt] = v;
        }
        #pragma unroll
        for (int i = 0; i < 4; ++i)
            #pragma unroll
            for (int dt = 0; dt < 3; ++dt)
                acc[i] = fmaf(wr[i][df * 3 + dt], xv[dt], acc[i]);
    }
    size_t obase = (((size_t)b * 32 + cg * 4) * 64 + f) * 512 + t;
    #pragma unroll
    for (int i = 0; i < 4; ++i) out[obase + (size_t)i * 64 * 512] = acc[i];
}

// ---------------- LN-over-f raw sums (dual-dtype input, NCHW) ----------------
// emits s and s2 (finalize_k converts to mean / rsqrt)
__global__ __launch_bounds__(256) void stats_k(const void* __restrict__ X, int isbf,
                                               float* __restrict__ sm, float* __restrict__ sr) {
    int idx = blockIdx.x * 256 + threadIdx.x;  // 16*32*512
    int t  = idx & 511;
    int bc = idx >> 9;
    size_t base = (size_t)bc * 64 * 512 + t;
    float s = 0.f, s2 = 0.f;
    #pragma unroll 8
    for (int f = 0; f < 64; ++f) {
        float v = isbf ? bf2f(((const u16*)X)[base + f * 512]) : ((const float*)X)[base + f * 512];
        s += v; s2 += v * v;
    }
    sm[idx] = s;
    sr[idx] = s2;
}

// ---------------- finalize raw sums -> (mean, rsqrt(var+eps)) in place ----------------
__global__ __launch_bounds__(256) void finalize_k(float* __restrict__ sm, float* __restrict__ sr) {
    int i = blockIdx.x * 256 + threadIdx.x;   // 262144
    float s = sm[i], s2 = sr[i];
    float m = s * (1.f / 64.f);
    float var = fmaxf(s2 * (1.f / 64.f) - m * m, 0.f);
    sm[i] = m;
    sr[i] = rsqrtf(var + 1e-5f);
}

// ---------------- apply LN+ReLU: NCHW (f32|bf16) -> Ha NHWC halo bf16 ----------------
__global__ __launch_bounds__(256) void apply_k(const void* __restrict__ in, int isbf,
                                               const float* __restrict__ sm, const float* __restrict__ sr,
                                               const float* __restrict__ g, const float* __restrict__ be,
                                               u16* __restrict__ Ha) {
    int f = blockIdx.x;
    int b = blockIdx.y;
    float gg = g[f], bb_ = be[f];
    for (int it = 0; it < 2; ++it) {
        int t = it * 256 + threadIdx.x;
        u32 pk[16];
        #pragma unroll
        for (int cp = 0; cp < 16; ++cp) {
            u32 w = 0;
            #pragma unroll
            for (int half = 0; half < 2; ++half) {
                int ci = cp * 2 + half;
                size_t xi = (((size_t)b * 32 + ci) * 64 + f) * 512 + t;
                float xv = isbf ? bf2f(((const u16*)in)[xi]) : ((const float*)in)[xi];
                int si = (b * 32 + ci) * 512 + t;
                float hv = fmaxf((xv - sm[si]) * sr[si] * gg + bb_, 0.f);
                w |= ((u32)f2bf(hv)) << (half * 16);
            }
            pk[cp] = w;
        }
        u32* orow = (u32*)(Ha + (size_t)b * HA_BSTRIDE + ((size_t)(f + 1) * 514 + (t + 1)) * 32);
        #pragma unroll
        for (int q = 0; q < 16; ++q) orow[q] = pk[q];
    }
}

// ---------------- conv32 k3 s1 p1 via MFMA + fused LN-stats accumulation ----------------
// Pipeline as R3 (verified): per wave per tile exactly 6 GLL; counted vmcnt; raw barriers.
// Fused stats: epilogue values' per-thread f-partials -> LDS (bijective per-wave slots,
// [17]-padded) -> 4-wave reduce -> global atomicAdd into SM/SR (4 atomics/thread/tile).
// vmcnt waits are exact per (hasres, dostats) variant issue counts.
#define CVL 4
__global__ __launch_bounds__(256) void convm_k(const u16* __restrict__ Ha, void* __restrict__ out,
                                               const float* __restrict__ w, const float* __restrict__ bias,
                                               const float* __restrict__ res,
                                               float* __restrict__ smx, float* __restrict__ srx) {
    __shared__ __align__(16) u16 act[2][1536 * 8];   // 2 x 24576 B
    __shared__ float ssS[4][32][17];                 // 8704 B  [wv][co][j pad17]
    __shared__ float ssQ[4][32][17];                 // 8704 B
    int F0    = blockIdx.x * 16;
    int tbase = blockIdx.y * 64;
    int b     = blockIdx.z;
    const u16* Hb = Ha + (size_t)b * HA_BSTRIDE;
    int tid  = threadIdx.x;
    int lane = tid & 63;
    int wv   = tid >> 6;
    int quad = lane >> 4;
    int r    = lane & 15;
    int hasres  = (res != nullptr);
    int dostats = (smx != nullptr);

    int ufp[6], utp[6], uq[6];
    #pragma unroll
    for (int it = 0; it < 6; ++it) {
        int u = it * 256 + tid;
        int u2 = (u < 1296) ? u : (u - 1296);
        int fp = u2 / 72;
        int rem = u2 - fp * 72;
        ufp[it] = fp; utp[it] = rem >> 2; uq[it] = rem & 3;
    }

    auto stage = [&](int tile, int bw) {
        int t00 = tbase + tile * 16;
        #pragma unroll
        for (int it = 0; it < 6; ++it) {
            int u = it * 256 + tid;
            GLL(Hb + ((size_t)(F0 + ufp[it]) * 514 + (t00 + utp[it])) * 32 + uq[it] * 8,
                &act[bw][u * 8]);
        }
    };

    short8 bfrag[3][3][2];
    #pragma unroll
    for (int df = 0; df < 3; ++df)
        #pragma unroll
        for (int dt = 0; dt < 3; ++dt)
            #pragma unroll
            for (int ct = 0; ct < 2; ++ct) {
                short8 v;
                #pragma unroll
                for (int j = 0; j < 8; ++j) {
                    int co = ct * 16 + r, ci = quad * 8 + j;
                    v[j] = (short)f2bf(w[(co * 32 + ci) * 9 + df * 3 + dt]);
                }
                bfrag[df][dt][ct] = v;
            }

    WAITVM(0);   // drain weight loads: vm FIFO starts clean
    SBAR();
    stage(0, 0);
    SBAR();

    int fb = wv * 4;   // this wave's local f base (4 f-rows per wave)
    #pragma unroll 1
    for (int i = 0; i < CVL; ++i) {
        if (i < CVL - 1) stage(i + 1, (i + 1) & 1);
        SBAR();
        // exact counted waits: younger ops = epi(i-1) [16res/8] + atom(i-1) [4 if stats] + stage(i+1) [6]
        if (i == 0)           { WAITVM(6); }
        else if (i < CVL - 1) {
            if (hasres) { if (dostats) WAITVM(26); else WAITVM(22); }
            else        { if (dostats) WAITVM(18); else WAITVM(14); }
        } else {
            if (hasres) { if (dostats) WAITVM(20); else WAITVM(16); }
            else        { if (dostats) WAITVM(12); else WAITVM(8); }
        }
        SBAR();
        __builtin_amdgcn_s_barrier();   // all waves' stage_i done
        SBAR();

        const u16* ab = act[i & 1];
        floatx4 acc[4][2];
        #pragma unroll
        for (int ii = 0; ii < 4; ++ii)
            #pragma unroll
            for (int j = 0; j < 2; ++j)
                #pragma unroll
                for (int k = 0; k < 4; ++k) acc[ii][j][k] = 0.f;

        #pragma unroll
        for (int fh = 0; fh < 6; ++fh) {
            short8 af[3];
            #pragma unroll
            for (int dt = 0; dt < 3; ++dt)
                af[dt] = *(const short8*)&ab[((fb + fh) * 18 + (r + dt)) * 32 + quad * 8];
            #pragma unroll
            for (int df = 0; df < 3; ++df) {
                int rel = fh - df;
                if (rel < 0 || rel >= 4) continue;
                #pragma unroll
                for (int dt = 0; dt < 3; ++dt)
                    #pragma unroll
                    for (int ct = 0; ct < 2; ++ct)
                        acc[rel][ct] = __builtin_amdgcn_mfma_f32_16x16x32_bf16(
                            af[dt], bfrag[df][dt][ct], acc[rel][ct], 0, 0, 0);
            }
        }

        int t0 = tbase + i * 16;
        int tt = t0 + quad * 4;
        float ps[2][4], p2s[2][4];
        #pragma unroll
        for (int ct = 0; ct < 2; ++ct)
            #pragma unroll
            for (int rg = 0; rg < 4; ++rg) { ps[ct][rg] = 0.f; p2s[ct][rg] = 0.f; }

        #pragma unroll
        for (int rel = 0; rel < 4; ++rel)
            #pragma unroll
            for (int ct = 0; ct < 2; ++ct) {
                int f  = F0 + fb + rel;
                int co = ct * 16 + r;
                size_t base = (((size_t)b * 32 + co) * 64 + f) * 512 + tt;
                float bs = bias[co];
                float v4[4];
                if (hasres) {
                    float4 rv = *(const float4*)(res + base);
                    v4[0] = acc[rel][ct][0] + bs + rv.x;
                    v4[1] = acc[rel][ct][1] + bs + rv.y;
                    v4[2] = acc[rel][ct][2] + bs + rv.z;
                    v4[3] = acc[rel][ct][3] + bs + rv.w;
                    float4 o = {v4[0], v4[1], v4[2], v4[3]};
                    *(float4*)((float*)out + base) = o;
                } else {
                    v4[0] = acc[rel][ct][0] + bs;
                    v4[1] = acc[rel][ct][1] + bs;
                    v4[2] = acc[rel][ct][2] + bs;
                    v4[3] = acc[rel][ct][3] + bs;
                    ushort4 o;
                    o.x = f2bf(v4[0]); o.y = f2bf(v4[1]);
                    o.z = f2bf(v4[2]); o.w = f2bf(v4[3]);
                    *(ushort4*)((u16*)out + base) = o;
                }
                #pragma unroll
                for (int rg = 0; rg < 4; ++rg) {
                    ps[ct][rg]  += v4[rg];
                    p2s[ct][rg] += v4[rg] * v4[rg];
                }
            }

        if (dostats) {
            // bijective per-wave LDS slots: (wv, co, j=quad*4+rg)
            #pragma unroll
            for (int ct = 0; ct < 2; ++ct)
                #pragma unroll
                for (int rg = 0; rg < 4; ++rg) {
                    int co = ct * 16 + r;
                    int j  = quad * 4 + rg;
                    ssS[wv][co][j] = ps[ct][rg];
                    ssQ[wv][co][j] = p2s[ct][rg];
                }
            WAITLG();
            SBAR();
            __builtin_amdgcn_s_barrier();   // all partials written
            SBAR();
            #pragma unroll
            for (int s_ = 0; s_ < 2; ++s_) {
                int slot = s_ * 256 + tid;
                int co = slot >> 4, j = slot & 15;
                float a = ssS[0][co][j] + ssS[1][co][j] + ssS[2][co][j] + ssS[3][co][j];
                float q = ssQ[0][co][j] + ssQ[1][co][j] + ssQ[2][co][j] + ssQ[3][co][j];
                int gi = ((b * 32 + co) << 9) + t0 + j;
                atomicAdd(&smx[gi], a);
                atomicAdd(&srx[gi], q);
            }
        }
        SBAR();
        __builtin_amdgcn_s_barrier();   // all waves done reading buf[i&1] / ss before reuse
        SBAR();
    }
}

// ---------------- transpose X (b,c,f,t) f32 -> A[(t*16+b)][(c*64+f)] bf16 ----------------
__global__ __launch_bounds__(256) void transpose_k(const float* __restrict__ X, u16* __restrict__ A) {
    __shared__ float tile[64][65];
    int t0 = blockIdx.x * 64;
    int c  = blockIdx.y;
    int b  = blockIdx.z;
    const float* p = X + (((size_t)b * 32 + c) * 64) * 512 + t0;
    #pragma unroll
    for (int i = 0; i < 16; ++i) {
        int f = i * 4 + (threadIdx.x >> 6);
        int t = threadIdx.x & 63;
        tile[f][t] = p[(size_t)f * 512 + t];
    }
    __syncthreads();
    #pragma unroll
    for (int i = 0; i < 16; ++i) {
        int t = i * 4 + (threadIdx.x >> 6);
        int f = threadIdx.x & 63;
        A[((size_t)(t0 + t) * 16 + b) * 2048 + c * 64 + f] = f2bf(tile[f][t]);
    }
}

// ---------------- row layernorm, f32 in -> bf16 out ----------------
__global__ __launch_bounds__(256) void lnlast_k(const float* __restrict__ X, u16* __restrict__ Y,
                                                const float* __restrict__ g, const float* __restrict__ bt,
                                                int width) {
    int row = blockIdx.x;
    const float* p = X + (size_t)row * width;
    float s = 0.f, s2 = 0.f;
    for (int i = threadIdx.x; i < width; i += 256) { float v = p[i]; s += v; s2 += v * v; }
    #pragma unroll
    for (int off = 32; off; off >>= 1) { s += __shfl_down(s, off); s2 += __shfl_down(s2, off); }
    __shared__ float red[4][2];
    int wv = threadIdx.x >> 6;
    if ((threadIdx.x & 63) == 0) { red[wv][0] = s; red[wv][1] = s2; }
    __syncthreads();
    if (threadIdx.x == 0) {
        float a = 0.f, b2 = 0.f;
        for (int i = 0; i < 4; ++i) { a += red[i][0]; b2 += red[i][1]; }
        float m = a / width;
        float var = fmaxf(b2 / width - m * m, 0.f);
        red[0][0] = m; red[0][1] = rsqrtf(var + 1e-5f);
    }
    __syncthreads();
    float m = red[0][0], rs = red[0][1];
    u16* q = Y + (size_t)row * width;
    for (int i = threadIdx.x; i < width; i += 256)
        q[i] = f2bf((p[i] - m) * rs * g[i] + bt[i]);
}

// ---------------- MFMA GEMM: C = A @ Bt^T, 128x128, BK=32 (R5-verified) ----------------
// 3-buffer counted-vmcnt pipeline: prologue stages k0..k2, steady loop waits vmcnt(8)
// (stages i+1,i+2 in flight across raw barriers), computes buf i%3, stages i+3 into the
// just-freed buffer. Exactly 4 GLL/wave/stage. Identity block mapping (R4: XCD swizzle
// quadrupled FETCH_SIZE on these L3-fit inputs). R6's BK=64/2-buffer variant regressed.
__global__ __launch_bounds__(256) void gemm_bt(const u16* __restrict__ A, const u16* __restrict__ A2,
                                               int lda, const u16* __restrict__ Bt, int ldb,
                                               void* __restrict__ C, void* __restrict__ C2,
                                               int ldc, int nsplit,
                                               const float* __restrict__ bias, int relu, int K,
                                               int obf) {
    __shared__ __align__(16) u16 As[3][128 * 32];
    __shared__ __align__(16) u16 Bs[3][128 * 32];
    int tid  = threadIdx.x;
    int bm   = blockIdx.x * 128;
    int bn   = blockIdx.y * 128;

    const u16* Ab = A;
    void* Cb = C;
    int cn = bn;
    if (bn >= nsplit) { Ab = A2; Cb = C2; cn = bn - nsplit; }

    int lane = tid & 63;
    int wv   = tid >> 6;
    int quad = lane >> 4;
    int r    = lane & 15;
    int wm   = (wv >> 1) * 64;
    int wn   = (wv & 1) * 64;

    floatx4 acc[4][4];
    #pragma unroll
    for (int i = 0; i < 4; ++i)
        #pragma unroll
        for (int j = 0; j < 4; ++j)
            #pragma unroll
            for (int k = 0; k < 4; ++k) acc[i][j][k] = 0.f;

    int row0 = tid >> 2;
    int ks0  = ((tid & 3) ^ ((tid >> 3) & 3)) * 8;   // XOR swizzled k-seg
    const u16* Ab1 = Ab + (size_t)(bm + row0) * lda + ks0;
    const u16* Ab2 = Ab + (size_t)(bm + 64 + row0) * lda + ks0;
    const u16* Bb1 = Bt + (size_t)(bn + row0) * ldb + ks0;
    const u16* Bb2 = Bt + (size_t)(bn + 64 + row0) * ldb + ks0;

    auto stage = [&](int ks, int bw) {
        int k0 = ks * 32;
        GLL(Ab1 + k0, &As[bw][tid * 8]);
        GLL(Ab2 + k0, &As[bw][2048 + tid * 8]);
        GLL(Bb1 + k0, &Bs[bw][tid * 8]);
        GLL(Bb2 + k0, &Bs[bw][2048 + tid * 8]);
    };

    int nk = K >> 5;            // >= 3 for all launches
    WAITVM(0);                  // vm FIFO starts clean
    SBAR();
    stage(0, 0); stage(1, 1); stage(2, 2);
    SBAR();

    int col = (quad ^ ((r >> 1) & 3)) * 8;            // read-side un-swizzle
    int bc = 0;                                       // rotating compute buffer
    #pragma unroll 1
    for (int i = 0; i < nk; ++i) {
        if (i + 2 < nk)       { WAITVM(8); }
        else if (i + 1 < nk)  { WAITVM(4); }
        else                  { WAITVM(0); }
        SBAR();
        __builtin_amdgcn_s_barrier();   // all waves' stage(i) complete
        SBAR();

        const u16* as = As[bc];
        const u16* bs = Bs[bc];
        short8 af[4], bf[4];
        #pragma unroll
        for (int mi = 0; mi < 4; ++mi) af[mi] = *(const short8*)&as[(wm + mi * 16 + r) * 32 + col];
        #pragma unroll
        for (int ni = 0; ni < 4; ++ni) bf[ni] = *(const short8*)&bs[(wn + ni * 16 + r) * 32 + col];
        #pragma unroll
        for (int mi = 0; mi < 4; ++mi)
            #pragma unroll
            for (int ni = 0; ni < 4; ++ni)
                acc[mi][ni] = __builtin_amdgcn_mfma_f32_16x16x32_bf16(af[mi], bf[ni], acc[mi][ni], 0, 0, 0);

        SBAR();
        __builtin_amdgcn_s_barrier();   // all waves done reading buf bc
        SBAR();
        if (i + 3 < nk) stage(i + 3, bc);   // reuse just-freed buffer
        bc = (bc == 2) ? 0 : bc + 1;
    }

    #pragma unroll
    for (int mi = 0; mi < 4; ++mi)
        #pragma unroll
        for (int ni = 0; ni < 4; ++ni) {
            int ccol = cn + wn + ni * 16 + r;
            float bsv = bias ? bias[ccol] : 0.f;
            #pragma unroll
            for (int reg = 0; reg < 4; ++reg) {
                int row = bm + wm + mi * 16 + quad * 4 + reg;
                float v = acc[mi][ni][reg] + bsv;
                if (relu) v = fmaxf(v, 0.f);
                if (obf) ((u16*)Cb)[(size_t)row * ldc + ccol] = f2bf(v);
                else     ((float*)Cb)[(size_t)row * ldc + ccol] = v;
            }
        }
}

// ---------------- SRU scan: 1 wave/block, 4-buffer counted-vmcnt pipeline ----------------
#define TC 256
__global__ __launch_bounds__(64) void scan_k(const u16* __restrict__ Uf, const u16* __restrict__ Ub,
                                             const float* __restrict__ Xp, float* __restrict__ Xn,
                                             float* __restrict__ cstate, const float* __restrict__ vv,
                                             const float* __restrict__ bb, int t0f, int t0b, int init) {
    __shared__ __align__(16) char lds[4][10240];
    int tid = threadIdx.x;
    int d   = blockIdx.x >> 7;
    int idx = blockIdx.x & 127;
    int b   = idx >> 3;
    int h0  = (idx & 7) * 64;
    int h   = h0 + tid;
    int gid = d * 8192 + idx * 64 + tid;

    float v0 = vv[(d * 2 + 0) * 512 + h];
    float v1 = vv[(d * 2 + 1) * 512 + h];
    float b0 = bb[(d * 2 + 0) * 512 + h];
    float b1 = bb[(d * 2 + 1) * 512 + h];
    const u16* U = d ? Ub : Uf;
    int t0 = d ? t0b : t0f;
    float* ob = Xn + (size_t)b * 1024 + d * 512 + h;
    float cc = init ? 0.f : cstate[gid];
    int tstp = d ? -16384 : 16384;

    const char* gp[10];
    int dlt[10];
    #pragma unroll
    for (int it = 0; it < 10; ++it) {
        int u = it * 64 + tid;
        int s = u / 40;
        int j = u - s * 40;
        int sl0 = d ? (TC - 1 - s) : s;
        if (j < 24) {
            int k = j >> 3, jj = j & 7;
            gp[it] = (const char*)(U + ((size_t)(sl0 * 16 + b) * 1536 + k * 512 + h0 + jj * 8));
            dlt[it] = d ? -786432 : 786432;        // 16 slots * 16 rows * 1536 * 2B
        } else {
            gp[it] = (const char*)(Xp + ((size_t)(t0 + sl0) * 16384 + (size_t)b * 1024 + d * 512 + h0 + (j - 24) * 4));
            dlt[it] = d ? -1048576 : 1048576;      // 16 * 16384 * 4B
        }
    }
    char* lbase = (char*)&lds[0][0] + tid * 16;
    auto stage = [&](int bw) {
        char* lb = lbase + bw * 10240;
        #pragma unroll
        for (int it = 0; it < 10; ++it) {
            GLL(gp[it], lb + it * 1024);
            gp[it] += dlt[it];
        }
    };

    asm volatile("s_waitcnt vmcnt(0)" ::: "memory");   // drain param loads: counts start at 0
    SBAR();
    stage(0);
    stage(1);
    stage(2);
    SBAR();

    #pragma unroll 1
    for (int tk = 0; tk < 16; ++tk) {
        switch (tk) {
            case 0:  WAITVM(20); break;   // s1+s2
            case 1:  WAITVM(36); break;   // s2+c0+s3
            case 14: WAITVM(42); break;   // c12+s15+c13
            case 15: WAITVM(32); break;   // c13+c14
            default: WAITVM(52); break;   // c+s+c+s
        }
        SBAR();
        const char* Bb = (const char*)&lds[0][0] + (size_t)(tk & 3) * 10240;
        float* op = ob + (size_t)(t0 + (d ? (TC - 1 - tk * 16) : tk * 16)) * 16384;
        #pragma unroll
        for (int s = 0; s < 16; ++s) {
            const char* sb = Bb + s * 640;
            float u0 = bf2f(*(const u16*)(sb + tid * 2));
            float fp = bf2f(*(const u16*)(sb + 128 + tid * 2)) + b0;
            float rp = bf2f(*(const u16*)(sb + 256 + tid * 2)) + b1;
            float xr = *(const float*)(sb + 384 + tid * 4);
            float f = 1.f / (1.f + __expf(-(fp + v0 * cc)));
            float r = 1.f / (1.f + __expf(-(rp + v1 * cc)));
            cc = f * cc + (1.f - f) * u0;
            float th = 1.f - 2.f / (__expf(2.f * cc) + 1.f);
            *op = r * th + (1.f - r) * xr;
            op += tstp;
        }
        SBAR();
        if (tk < 13) stage((tk + 3) & 3);
        SBAR();
    }
    cstate[gid] = cc;
}

// ---------------- classifier head: 2 rows/block, k split 4-way, shuffle+LDS reduce ------
__global__ __launch_bounds__(256) void cls2_k(const float* __restrict__ FC1, const float* __restrict__ W2,
                                              const float* __restrict__ b2, void* __restrict__ out,
                                              const int* __restrict__ flag) {
    int isf32 = *flag;
    int tid = threadIdx.x;
    int rh = tid >> 7;              // row within block (0..1)
    int ks = (tid >> 5) & 3;        // k-segment (0..3), 128 k each
    int v  = tid & 31;              // output class lane
    int row = blockIdx.x * 2 + rh;
    const float* p = FC1 + (size_t)row * 512 + ks * 128;
    const float* wp = W2 + (size_t)ks * 128 * 29;
    float acc = 0.f;
    #pragma unroll 4
    for (int k = 0; k < 128; ++k) {
        float wv = (v < 29) ? wp[k * 29 + v] : 0.f;
        acc = fmaf(p[k], wv, acc);
    }
    acc += __shfl_xor(acc, 32);     // merge ks pairs within wave
    __shared__ float red[2][2][32];
    if ((tid & 63) < 32) red[rh][(tid >> 6) & 1][v] = acc;
    __syncthreads();
    if ((tid & 127) < 32 && v < 29) {
        float s = red[rh][0][v] + red[rh][1][v] + b2[v];
        int t = row >> 4, b = row & 15;
        size_t oi = ((size_t)b * 512 + t) * 29 + v;
        if (isf32) ((float*)out)[oi] = s;
        else       ((u16*)out)[oi]   = f2bf(s);
    }
}

// ---------------- launch ----------------
extern "C" void kernel_launch(void* const* d_in, const int* in_sizes, int n_in,
                              void* d_out, int out_size, void* d_ws, size_t ws_size,
                              hipStream_t stream) {
    const void* x      = d_in[0];
    const void* proj_w = d_in[11];
    const void* sru_w  = d_in[12];
    const void* cls_w1 = d_in[19];

    float* ws = (float*)d_ws;
    const size_t O_X    = 0;
    const size_t O_C    = 16777216;
    const size_t O_HA   = 25165824;
    const size_t O_SM   = 33850368;
    const size_t O_SR   = 34112512;
    const size_t O_CST  = 34374656;
    const size_t O_PARK = 34391040;
    const size_t O_FLAG = 34483488;
    const size_t TOTAL  = 34483504;   // 131.55 MiB
    if (ws_size < TOTAL * sizeof(float)) {
        fill_k<<<(out_size + 255) / 256, 256, 0, stream>>>((float*)d_out, out_size);
        return;
    }

    float* X   = ws + O_X;
    u16*   C   = (u16*)(ws + O_C);
    u16*   HA  = (u16*)(ws + O_HA);
    float* SM  = ws + O_SM;
    float* SR  = ws + O_SR;
    float* CST = ws + O_CST;
    float* PK  = ws + O_PARK;
    int*   FLG = (int*)(ws + O_FLAG);

    u16*   Abf = (u16*)(ws + O_C);
    u16*   BtP = (u16*)(ws + 0);
    float* XP0 = ws + 25165824;
    u16*   XL  = (u16*)(ws + 0);
    float* XP1 = ws + 4194304;
    u16*   Uf  = (u16*)(ws + 12582912);
    u16*   Ub  = (u16*)(ws + 15728640);
    u16*   BtS = (u16*)(ws + 18874368);
    u16*   BtC = (u16*)(ws + O_SM);
    float* FC1 = ws + 12582912;

    float* p_cnn_w = PK + 0;      float* p_cnn_b = PK + 288;
    float* p_rw1   = PK + 320;    float* p_rb1   = PK + 27968;
    float* p_rw2   = PK + 28064;  float* p_rb2   = PK + 55712;
    float* p_l1g   = PK + 55808;  float* p_l1b   = PK + 56000;
    float* p_l2g   = PK + 56192;  float* p_l2b   = PK + 56384;
    float* p_sv    = PK + 56576;  float* p_sb    = PK + 62720;
    float* p_slng  = PK + 68864;  float* p_slnb  = PK + 71936;
    float* p_clng  = PK + 75008;  float* p_clnb  = PK + 76032;
    float* p_cb1   = PK + 77056;  float* p_cw2   = PK + 77568;
    float* p_cb2   = PK + 92416;

    sniff_k<<<1, 256, 0, stream>>>((const u16*)x, FLG);

    CvtArgs ca;
    const int srcidx[19] = {1,2,3,4,5,6,7,8,9,10,13,14,15,16,17,18,20,21,22};
    const int lens[19]   = {288,32,27648,96,27648,96,192,192,192,192,6144,6144,3072,3072,1024,1024,512,14848,29};
    const int offs[19]   = {0,288,320,27968,28064,55712,55808,56000,56192,56384,56576,62720,68864,71936,75008,76032,77056,77568,92416};
    for (int i = 0; i < 19; ++i) { ca.src[i] = d_in[srcidx[i]]; ca.len[i] = lens[i]; ca.off[i] = offs[i]; }
    cvtall_k<<<dim3(108, 19), 256, 0, stream>>>(ca, PK, FLG);

    zero_k<<<2048, 256, 0, stream>>>((float4*)HA, 2171136);
    conv1_k<<<16384, 256, 0, stream>>>(x, p_cnn_w, p_cnn_b, X, FLG);

    stats_k<<<1024, 256, 0, stream>>>(X, 0, SM, SR);   // raw sums
    for (int i = 0; i < 3; ++i) {
        finalize_k<<<1024, 256, 0, stream>>>(SM, SR);
        apply_k<<<dim3(64, 16), 256, 0, stream>>>(X, 0, SM, SR, p_l1g + i * 64, p_l1b + i * 64, HA);
        zero_k<<<512, 256, 0, stream>>>((float4*)SM, 131072);   // SM+SR contiguous
        convm_k<<<dim3(4, 8, 16), 256, 0, stream>>>(HA, C, p_rw1 + i * 9216, p_rb1 + i * 32,
                                                    nullptr, SM, SR);
        finalize_k<<<1024, 256, 0, stream>>>(SM, SR);
        apply_k<<<dim3(64, 16), 256, 0, stream>>>(C, 1, SM, SR, p_l2g + i * 64, p_l2b + i * 64, HA);
        if (i < 2) {
            zero_k<<<512, 256, 0, stream>>>((float4*)SM, 131072);
            convm_k<<<dim3(4, 8, 16), 256, 0, stream>>>(HA, X, p_rw2 + i * 9216, p_rb2 + i * 32,
                                                        X, SM, SR);
        } else {
            convm_k<<<dim3(4, 8, 16), 256, 0, stream>>>(HA, X, p_rw2 + i * 9216, p_rb2 + i * 32,
                                                        X, nullptr, nullptr);
        }
    }

    transpose_k<<<dim3(8, 32, 16), 256, 0, stream>>>(X, Abf);
    wtr_k<<<dim3(32, 16), 256, 0, stream>>>(proj_w, 1024, 0, BtP, 2048, FLG);
    gemm_bt<<<dim3(64, 8), 256, 0, stream>>>(Abf, Abf, 2048, BtP, 2048, XP0, XP0, 1024,
                                             1 << 30, nullptr, 0, 2048, 0);

    for (int l = 0; l < 3; ++l)
        wtr_k<<<dim3(16, 48), 256, 0, stream>>>(sru_w, 3072, (size_t)l * 3145728,
                                                BtS + (size_t)l * 3145728, 1024, FLG);
    wtr_k<<<dim3(16, 8), 256, 0, stream>>>(cls_w1, 512, 0, BtC, 1024, FLG);

    float* cur = XP0;
    float* nxt = XP1;
    for (int l = 0; l < 3; ++l) {
        lnlast_k<<<8192, 256, 0, stream>>>(cur, XL, p_slng + l * 1024, p_slnb + l * 1024, 1024);
        const u16* Btl = BtS + (size_t)l * 3145728;
        for (int j = 0; j < 2; ++j) {
            int t0f = j * TC;
            int t0b = (1 - j) * TC;
            gemm_bt<<<dim3(32, 24), 256, 0, stream>>>(XL + (size_t)t0f * 16 * 1024,
                                                      XL + (size_t)t0b * 16 * 1024, 1024,
                                                      Btl, 1024, Uf, Ub, 1536, 1536,
                                                      nullptr, 0, 1024, 1);
            scan_k<<<256, 64, 0, stream>>>(Uf, Ub, cur, nxt, CST,
                                           p_sv + l * 2048, p_sb + l * 2048, t0f, t0b, j == 0);
        }
        float* tmp = cur; cur = nxt; nxt = tmp;
    }

    lnlast_k<<<8192, 256, 0, stream>>>(cur, XL, p_clng, p_clnb, 1024);
    gemm_bt<<<dim3(64, 4), 256, 0, stream>>>(XL, XL, 1024, BtC, 1024, FC1, FC1, 512,
                                             1 << 30, p_cb1, 1, 1024, 0);
    cls2_k<<<4096, 256, 0, stream>>>(FC1, p_cw2, p_cb2, d_out, FLG);
}

// Round 8
// 1338.842 us; speedup vs baseline: 1.0761x; 1.0194x over previous
//
#include <hip/hip_runtime.h>

typedef unsigned short u16;
typedef unsigned int u32;
typedef __attribute__((ext_vector_type(8))) short short8;
typedef __attribute__((ext_vector_type(4))) float floatx4;

__device__ __forceinline__ float bf2f(u16 u) {
    union { unsigned int i; float f; } v; v.i = ((unsigned int)u) << 16; return v.f;
}
__device__ __forceinline__ u16 f2bf(float f) {
    union { float f; unsigned int i; } v; v.f = f;
    unsigned int i = v.i + 0x7fffu + ((v.i >> 16) & 1u);  // RNE
    return (u16)(i >> 16);
}

// async global->LDS, 16B per lane; LDS dest must be wave-uniform base + lane*16
#define GLL(g, l) __builtin_amdgcn_global_load_lds( \
    (const __attribute__((address_space(1))) void*)(g), \
    (__attribute__((address_space(3))) void*)(l), 16, 0, 0)

#define WAITVM(n) asm volatile("s_waitcnt vmcnt(" #n ")" ::: "memory")
#define WAITLG() asm volatile("s_waitcnt lgkmcnt(0)" ::: "memory")
#define SBAR() __builtin_amdgcn_sched_barrier(0)

// Ha halo tensor: [b][f_idx 0..65][t_idx 0..513 (pad 514)][ci 0..31] bf16
#define HA_BSTRIDE 1085568  // 66*514*32

// ---------------- dtype sniffer: flag=1 means inputs are float32 ----------------
__global__ __launch_bounds__(256) void sniff_k(const u16* __restrict__ x, int* __restrict__ flag) {
    __shared__ int red[4];
    int cnt = 0;
    for (int i = 0; i < 16; ++i) {
        u16 v = x[(threadIdx.x * 16 + i) * 2];
        int e = (v >> 7) & 0xFF;
        if (e >= 110 && e <= 135) cnt++;
    }
    #pragma unroll
    for (int off = 32; off; off >>= 1) cnt += __shfl_down(cnt, off);
    if ((threadIdx.x & 63) == 0) red[threadIdx.x >> 6] = cnt;
    __syncthreads();
    if (threadIdx.x == 0) {
        int tot = red[0] + red[1] + red[2] + red[3];
        *flag = (tot < 2048) ? 1 : 0;
    }
}

__device__ __forceinline__ float ldin(const void* p, size_t i, int isf32) {
    return isf32 ? ((const float*)p)[i] : bf2f(((const u16*)p)[i]);
}

// ---------------- canonicalize all params to f32 park (one launch) ----------------
struct CvtArgs {
    const void* src[19];
    int len[19];
    int off[19];
};
__global__ __launch_bounds__(256) void cvtall_k(CvtArgs a, float* __restrict__ dst,
                                                const int* __restrict__ flag) {
    int isf32 = *flag;
    int seg = blockIdx.y;
    int n = a.len[seg];
    const void* s = a.src[seg];
    float* d = dst + a.off[seg];
    for (int i = blockIdx.x * 256 + threadIdx.x; i < n; i += gridDim.x * 256)
        d[i] = ldin(s, i, isf32);
}

// ---------------- weight transpose: W[K][N] (dual dtype) -> Wt[N][K] bf16 ----------------
__global__ __launch_bounds__(256) void wtr_k(const void* __restrict__ W, int ldw, size_t wofs,
                                             u16* __restrict__ Wt, int ldt,
                                             const int* __restrict__ flag) {
    int isf32 = *flag;
    __shared__ u16 t[64][65];
    int k0 = blockIdx.x * 64, n0 = blockIdx.y * 64;
    int tid = threadIdx.x;
    #pragma unroll
    for (int i = 0; i < 16; ++i) {
        int kk = i * 4 + (tid >> 6), nn = tid & 63;
        t[kk][nn] = f2bf(ldin(W, wofs + (size_t)(k0 + kk) * ldw + n0 + nn, isf32));
    }
    __syncthreads();
    #pragma unroll
    for (int i = 0; i < 16; ++i) {
        int nn = i * 4 + (tid >> 6), kk = tid & 63;
        Wt[(size_t)(n0 + nn) * ldt + k0 + kk] = t[kk][nn];
    }
}

// ---------------- zero / guard fill ----------------
__global__ __launch_bounds__(256) void zero_k(float4* __restrict__ p, int n4) {
    float4 z = {0.f, 0.f, 0.f, 0.f};
    for (int i = blockIdx.x * 256 + threadIdx.x; i < n4; i += gridDim.x * 256) p[i] = z;
}
__global__ __launch_bounds__(256) void fill_k(float* __restrict__ p, int n) {
    int i = blockIdx.x * 256 + threadIdx.x;
    if (i < n) p[i] = 1.0e6f;
}

// ---------------- conv stem: 1->32, k3 s2 p1 -> X f32 NCHW; 4 co per thread ----------------
__global__ __launch_bounds__(256) void conv1_k(const void* __restrict__ x, const float* __restrict__ w,
                                               const float* __restrict__ bias, float* __restrict__ out,
                                               const int* __restrict__ flag) {
    int isf32 = *flag;
    int idx = blockIdx.x * 256 + threadIdx.x;   // 4,194,304 threads
    int t  = idx & 511;
    int f  = (idx >> 9) & 63;
    int cg = (idx >> 15) & 7;       // co = cg*4 + i
    int b  = idx >> 18;
    size_t xb = (size_t)b * 128 * 1024;

    float wr[4][9];
    #pragma unroll
    for (int i = 0; i < 4; ++i)
        #pragma unroll
        for (int k = 0; k < 9; ++k) wr[i][k] = w[(cg * 4 + i) * 9 + k];

    float acc[4];
    #pragma unroll
    for (int i = 0; i < 4; ++i) acc[i] = bias[cg * 4 + i];

    #pragma unroll
    for (int df = 0; df < 3; ++df) {
        int fi = 2 * f + df - 1;
        if (fi < 0 || fi >= 128) continue;       // wave-uniform branch
        size_t rowb = xb + (size_t)fi * 1024;
        float xv[3];
        #pragma unroll
        for (int dt = 0; dt < 3; ++dt) {
            int ti = 2 * t + dt - 1;
            float v = 0.f;
            if (ti >= 0 && ti < 1024) v = ldin(x, rowb + ti, isf32);
            xv[dt] = v;
        }
        #pragma unroll
        for (int i = 0; i < 4; ++i)
            #pragma unroll
            for (int dt = 0; dt < 3; ++dt)
                acc[i] = fmaf(wr[i][df * 3 + dt], xv[dt], acc[i]);
    }
    size_t obase = (((size_t)b * 32 + cg * 4) * 64 + f) * 512 + t;
    #pragma unroll
    for (int i = 0; i < 4; ++i) out[obase + (size_t)i * 64 * 512] = acc[i];
}

// ---------------- LN-over-f raw sums (dual-dtype input, NCHW) ----------------
// emits s and s2 (apply_k converts to mean / rsqrt inline)
__global__ __launch_bounds__(256) void stats_k(const void* __restrict__ X, int isbf,
                                               float* __restrict__ sm, float* __restrict__ sr) {
    int idx = blockIdx.x * 256 + threadIdx.x;  // 16*32*512
    int t  = idx & 511;
    int bc = idx >> 9;
    size_t base = (size_t)bc * 64 * 512 + t;
    float s = 0.f, s2 = 0.f;
    #pragma unroll 8
    for (int f = 0; f < 64; ++f) {
        float v = isbf ? bf2f(((const u16*)X)[base + f * 512]) : ((const float*)X)[base + f * 512];
        s += v; s2 += v * v;
    }
    sm[idx] = s;
    sr[idx] = s2;
}

// ---------------- apply LN+ReLU: NCHW (f32|bf16) -> Ha NHWC halo bf16 ----------------
// consumes RAW sums (s, s2); converts to (m, rs) inline — finalize_k folded in.
__global__ __launch_bounds__(256) void apply_k(const void* __restrict__ in, int isbf,
                                               const float* __restrict__ sm, const float* __restrict__ sr,
                                               const float* __restrict__ g, const float* __restrict__ be,
                                               u16* __restrict__ Ha) {
    int f = blockIdx.x;
    int b = blockIdx.y;
    float gg = g[f], bb_ = be[f];
    for (int it = 0; it < 2; ++it) {
        int t = it * 256 + threadIdx.x;
        u32 pk[16];
        #pragma unroll
        for (int cp = 0; cp < 16; ++cp) {
            u32 w = 0;
            #pragma unroll
            for (int half = 0; half < 2; ++half) {
                int ci = cp * 2 + half;
                size_t xi = (((size_t)b * 32 + ci) * 64 + f) * 512 + t;
                float xv = isbf ? bf2f(((const u16*)in)[xi]) : ((const float*)in)[xi];
                int si = (b * 32 + ci) * 512 + t;
                float s = sm[si], s2 = sr[si];
                float m = s * (1.f / 64.f);
                float var = fmaxf(s2 * (1.f / 64.f) - m * m, 0.f);
                float rs = rsqrtf(var + 1e-5f);
                float hv = fmaxf((xv - m) * rs * gg + bb_, 0.f);
                w |= ((u32)f2bf(hv)) << (half * 16);
            }
            pk[cp] = w;
        }
        u32* orow = (u32*)(Ha + (size_t)b * HA_BSTRIDE + ((size_t)(f + 1) * 514 + (t + 1)) * 32);
        #pragma unroll
        for (int q = 0; q < 16; ++q) orow[q] = pk[q];
    }
}

// ---------------- conv32 k3 s1 p1 via MFMA + fused LN-stats accumulation ----------------
// Pipeline as R3 (verified): per wave per tile exactly 6 GLL; counted vmcnt; raw barriers.
// Fused stats: epilogue values' per-thread f-partials -> LDS (bijective per-wave slots,
// [17]-padded) -> 4-wave reduce -> global atomicAdd into SM/SR (4 atomics/thread/tile).
// vmcnt waits are exact per (hasres, dostats) variant issue counts.
#define CVL 4
__global__ __launch_bounds__(256) void convm_k(const u16* __restrict__ Ha, void* __restrict__ out,
                                               const float* __restrict__ w, const float* __restrict__ bias,
                                               const float* __restrict__ res,
                                               float* __restrict__ smx, float* __restrict__ srx) {
    __shared__ __align__(16) u16 act[2][1536 * 8];   // 2 x 24576 B
    __shared__ float ssS[4][32][17];                 // 8704 B  [wv][co][j pad17]
    __shared__ float ssQ[4][32][17];                 // 8704 B
    int F0    = blockIdx.x * 16;
    int tbase = blockIdx.y * 64;
    int b     = blockIdx.z;
    const u16* Hb = Ha + (size_t)b * HA_BSTRIDE;
    int tid  = threadIdx.x;
    int lane = tid & 63;
    int wv   = tid >> 6;
    int quad = lane >> 4;
    int r    = lane & 15;
    int hasres  = (res != nullptr);
    int dostats = (smx != nullptr);

    int ufp[6], utp[6], uq[6];
    #pragma unroll
    for (int it = 0; it < 6; ++it) {
        int u = it * 256 + tid;
        int u2 = (u < 1296) ? u : (u - 1296);
        int fp = u2 / 72;
        int rem = u2 - fp * 72;
        ufp[it] = fp; utp[it] = rem >> 2; uq[it] = rem & 3;
    }

    auto stage = [&](int tile, int bw) {
        int t00 = tbase + tile * 16;
        #pragma unroll
        for (int it = 0; it < 6; ++it) {
            int u = it * 256 + tid;
            GLL(Hb + ((size_t)(F0 + ufp[it]) * 514 + (t00 + utp[it])) * 32 + uq[it] * 8,
                &act[bw][u * 8]);
        }
    };

    short8 bfrag[3][3][2];
    #pragma unroll
    for (int df = 0; df < 3; ++df)
        #pragma unroll
        for (int dt = 0; dt < 3; ++dt)
            #pragma unroll
            for (int ct = 0; ct < 2; ++ct) {
                short8 v;
                #pragma unroll
                for (int j = 0; j < 8; ++j) {
                    int co = ct * 16 + r, ci = quad * 8 + j;
                    v[j] = (short)f2bf(w[(co * 32 + ci) * 9 + df * 3 + dt]);
                }
                bfrag[df][dt][ct] = v;
            }

    WAITVM(0);   // drain weight loads: vm FIFO starts clean
    SBAR();
    stage(0, 0);
    SBAR();

    int fb = wv * 4;   // this wave's local f base (4 f-rows per wave)
    #pragma unroll 1
    for (int i = 0; i < CVL; ++i) {
        if (i < CVL - 1) stage(i + 1, (i + 1) & 1);
        SBAR();
        // exact counted waits: younger ops = epi(i-1) [16res/8] + atom(i-1) [4 if stats] + stage(i+1) [6]
        if (i == 0)           { WAITVM(6); }
        else if (i < CVL - 1) {
            if (hasres) { if (dostats) WAITVM(26); else WAITVM(22); }
            else        { if (dostats) WAITVM(18); else WAITVM(14); }
        } else {
            if (hasres) { if (dostats) WAITVM(20); else WAITVM(16); }
            else        { if (dostats) WAITVM(12); else WAITVM(8); }
        }
        SBAR();
        __builtin_amdgcn_s_barrier();   // all waves' stage_i done
        SBAR();

        const u16* ab = act[i & 1];
        floatx4 acc[4][2];
        #pragma unroll
        for (int ii = 0; ii < 4; ++ii)
            #pragma unroll
            for (int j = 0; j < 2; ++j)
                #pragma unroll
                for (int k = 0; k < 4; ++k) acc[ii][j][k] = 0.f;

        #pragma unroll
        for (int fh = 0; fh < 6; ++fh) {
            short8 af[3];
            #pragma unroll
            for (int dt = 0; dt < 3; ++dt)
                af[dt] = *(const short8*)&ab[((fb + fh) * 18 + (r + dt)) * 32 + quad * 8];
            #pragma unroll
            for (int df = 0; df < 3; ++df) {
                int rel = fh - df;
                if (rel < 0 || rel >= 4) continue;
                #pragma unroll
                for (int dt = 0; dt < 3; ++dt)
                    #pragma unroll
                    for (int ct = 0; ct < 2; ++ct)
                        acc[rel][ct] = __builtin_amdgcn_mfma_f32_16x16x32_bf16(
                            af[dt], bfrag[df][dt][ct], acc[rel][ct], 0, 0, 0);
            }
        }

        int t0 = tbase + i * 16;
        int tt = t0 + quad * 4;
        float ps[2][4], p2s[2][4];
        #pragma unroll
        for (int ct = 0; ct < 2; ++ct)
            #pragma unroll
            for (int rg = 0; rg < 4; ++rg) { ps[ct][rg] = 0.f; p2s[ct][rg] = 0.f; }

        #pragma unroll
        for (int rel = 0; rel < 4; ++rel)
            #pragma unroll
            for (int ct = 0; ct < 2; ++ct) {
                int f  = F0 + fb + rel;
                int co = ct * 16 + r;
                size_t base = (((size_t)b * 32 + co) * 64 + f) * 512 + tt;
                float bs = bias[co];
                float v4[4];
                if (hasres) {
                    float4 rv = *(const float4*)(res + base);
                    v4[0] = acc[rel][ct][0] + bs + rv.x;
                    v4[1] = acc[rel][ct][1] + bs + rv.y;
                    v4[2] = acc[rel][ct][2] + bs + rv.z;
                    v4[3] = acc[rel][ct][3] + bs + rv.w;
                    float4 o = {v4[0], v4[1], v4[2], v4[3]};
                    *(float4*)((float*)out + base) = o;
                } else {
                    v4[0] = acc[rel][ct][0] + bs;
                    v4[1] = acc[rel][ct][1] + bs;
                    v4[2] = acc[rel][ct][2] + bs;
                    v4[3] = acc[rel][ct][3] + bs;
                    ushort4 o;
                    o.x = f2bf(v4[0]); o.y = f2bf(v4[1]);
                    o.z = f2bf(v4[2]); o.w = f2bf(v4[3]);
                    *(ushort4*)((u16*)out + base) = o;
                }
                #pragma unroll
                for (int rg = 0; rg < 4; ++rg) {
                    ps[ct][rg]  += v4[rg];
                    p2s[ct][rg] += v4[rg] * v4[rg];
                }
            }

        if (dostats) {
            // bijective per-wave LDS slots: (wv, co, j=quad*4+rg)
            #pragma unroll
            for (int ct = 0; ct < 2; ++ct)
                #pragma unroll
                for (int rg = 0; rg < 4; ++rg) {
                    int co = ct * 16 + r;
                    int j  = quad * 4 + rg;
                    ssS[wv][co][j] = ps[ct][rg];
                    ssQ[wv][co][j] = p2s[ct][rg];
                }
            WAITLG();
            SBAR();
            __builtin_amdgcn_s_barrier();   // all partials written
            SBAR();
            #pragma unroll
            for (int s_ = 0; s_ < 2; ++s_) {
                int slot = s_ * 256 + tid;
                int co = slot >> 4, j = slot & 15;
                float a = ssS[0][co][j] + ssS[1][co][j] + ssS[2][co][j] + ssS[3][co][j];
                float q = ssQ[0][co][j] + ssQ[1][co][j] + ssQ[2][co][j] + ssQ[3][co][j];
                int gi = ((b * 32 + co) << 9) + t0 + j;
                atomicAdd(&smx[gi], a);
                atomicAdd(&srx[gi], q);
            }
        }
        SBAR();
        __builtin_amdgcn_s_barrier();   // all waves done reading buf[i&1] / ss before reuse
        SBAR();
    }
}

// ---------------- transpose X (b,c,f,t) f32 -> A[(t*16+b)][(c*64+f)] bf16 ----------------
__global__ __launch_bounds__(256) void transpose_k(const float* __restrict__ X, u16* __restrict__ A) {
    __shared__ float tile[64][65];
    int t0 = blockIdx.x * 64;
    int c  = blockIdx.y;
    int b  = blockIdx.z;
    const float* p = X + (((size_t)b * 32 + c) * 64) * 512 + t0;
    #pragma unroll
    for (int i = 0; i < 16; ++i) {
        int f = i * 4 + (threadIdx.x >> 6);
        int t = threadIdx.x & 63;
        tile[f][t] = p[(size_t)f * 512 + t];
    }
    __syncthreads();
    #pragma unroll
    for (int i = 0; i < 16; ++i) {
        int t = i * 4 + (threadIdx.x >> 6);
        int f = threadIdx.x & 63;
        A[((size_t)(t0 + t) * 16 + b) * 2048 + c * 64 + f] = f2bf(tile[f][t]);
    }
}

// ---------------- row layernorm (width=1024), float4-vectorized, f32 in -> bf16 out -----
__global__ __launch_bounds__(256) void lnlast_k(const float* __restrict__ X, u16* __restrict__ Y,
                                                const float* __restrict__ g, const float* __restrict__ bt,
                                                int width) {
    int row = blockIdx.x;
    int tid = threadIdx.x;
    const float* p = X + (size_t)row * width;
    float4 v4 = *(const float4*)(p + tid * 4);     // width==1024: exactly 4 per thread
    float s  = v4.x + v4.y + v4.z + v4.w;
    float s2 = v4.x * v4.x + v4.y * v4.y + v4.z * v4.z + v4.w * v4.w;
    #pragma unroll
    for (int off = 32; off; off >>= 1) { s += __shfl_down(s, off); s2 += __shfl_down(s2, off); }
    __shared__ float red[4][2];
    int wv = tid >> 6;
    if ((tid & 63) == 0) { red[wv][0] = s; red[wv][1] = s2; }
    __syncthreads();
    if (tid == 0) {
        float a = 0.f, b2 = 0.f;
        for (int i = 0; i < 4; ++i) { a += red[i][0]; b2 += red[i][1]; }
        float m = a / width;
        float var = fmaxf(b2 / width - m * m, 0.f);
        red[0][0] = m; red[0][1] = rsqrtf(var + 1e-5f);
    }
    __syncthreads();
    float m = red[0][0], rs = red[0][1];
    float4 g4 = *(const float4*)(g + tid * 4);
    float4 b4 = *(const float4*)(bt + tid * 4);
    ushort4 o;
    o.x = f2bf((v4.x - m) * rs * g4.x + b4.x);
    o.y = f2bf((v4.y - m) * rs * g4.y + b4.y);
    o.z = f2bf((v4.z - m) * rs * g4.z + b4.z);
    o.w = f2bf((v4.w - m) * rs * g4.w + b4.w);
    *(ushort4*)(Y + (size_t)row * width + tid * 4) = o;
}

// ---------------- MFMA GEMM: C = A @ Bt^T, 128x128, BK=32 (R5-verified) ----------------
// 3-buffer counted-vmcnt pipeline: prologue stages k0..k2, steady loop waits vmcnt(8)
// (stages i+1,i+2 in flight across raw barriers), computes buf i%3, stages i+3 into the
// just-freed buffer. Exactly 4 GLL/wave/stage. Identity block mapping (R4: XCD swizzle
// quadrupled FETCH_SIZE on these L3-fit inputs). R6's BK=64/2-buffer variant regressed.
__global__ __launch_bounds__(256) void gemm_bt(const u16* __restrict__ A, const u16* __restrict__ A2,
                                               int lda, const u16* __restrict__ Bt, int ldb,
                                               void* __restrict__ C, void* __restrict__ C2,
                                               int ldc, int nsplit,
                                               const float* __restrict__ bias, int relu, int K,
                                               int obf) {
    __shared__ __align__(16) u16 As[3][128 * 32];
    __shared__ __align__(16) u16 Bs[3][128 * 32];
    int tid  = threadIdx.x;
    int bm   = blockIdx.x * 128;
    int bn   = blockIdx.y * 128;

    const u16* Ab = A;
    void* Cb = C;
    int cn = bn;
    if (bn >= nsplit) { Ab = A2; Cb = C2; cn = bn - nsplit; }

    int lane = tid & 63;
    int wv   = tid >> 6;
    int quad = lane >> 4;
    int r    = lane & 15;
    int wm   = (wv >> 1) * 64;
    int wn   = (wv & 1) * 64;

    floatx4 acc[4][4];
    #pragma unroll
    for (int i = 0; i < 4; ++i)
        #pragma unroll
        for (int j = 0; j < 4; ++j)
            #pragma unroll
            for (int k = 0; k < 4; ++k) acc[i][j][k] = 0.f;

    int row0 = tid >> 2;
    int ks0  = ((tid & 3) ^ ((tid >> 3) & 3)) * 8;   // XOR swizzled k-seg
    const u16* Ab1 = Ab + (size_t)(bm + row0) * lda + ks0;
    const u16* Ab2 = Ab + (size_t)(bm + 64 + row0) * lda + ks0;
    const u16* Bb1 = Bt + (size_t)(bn + row0) * ldb + ks0;
    const u16* Bb2 = Bt + (size_t)(bn + 64 + row0) * ldb + ks0;

    auto stage = [&](int ks, int bw) {
        int k0 = ks * 32;
        GLL(Ab1 + k0, &As[bw][tid * 8]);
        GLL(Ab2 + k0, &As[bw][2048 + tid * 8]);
        GLL(Bb1 + k0, &Bs[bw][tid * 8]);
        GLL(Bb2 + k0, &Bs[bw][2048 + tid * 8]);
    };

    int nk = K >> 5;            // >= 3 for all launches
    WAITVM(0);                  // vm FIFO starts clean
    SBAR();
    stage(0, 0); stage(1, 1); stage(2, 2);
    SBAR();

    int col = (quad ^ ((r >> 1) & 3)) * 8;            // read-side un-swizzle
    int bc = 0;                                       // rotating compute buffer
    #pragma unroll 1
    for (int i = 0; i < nk; ++i) {
        if (i + 2 < nk)       { WAITVM(8); }
        else if (i + 1 < nk)  { WAITVM(4); }
        else                  { WAITVM(0); }
        SBAR();
        __builtin_amdgcn_s_barrier();   // all waves' stage(i) complete
        SBAR();

        const u16* as = As[bc];
        const u16* bs = Bs[bc];
        short8 af[4], bf[4];
        #pragma unroll
        for (int mi = 0; mi < 4; ++mi) af[mi] = *(const short8*)&as[(wm + mi * 16 + r) * 32 + col];
        #pragma unroll
        for (int ni = 0; ni < 4; ++ni) bf[ni] = *(const short8*)&bs[(wn + ni * 16 + r) * 32 + col];
        #pragma unroll
        for (int mi = 0; mi < 4; ++mi)
            #pragma unroll
            for (int ni = 0; ni < 4; ++ni)
                acc[mi][ni] = __builtin_amdgcn_mfma_f32_16x16x32_bf16(af[mi], bf[ni], acc[mi][ni], 0, 0, 0);

        SBAR();
        __builtin_amdgcn_s_barrier();   // all waves done reading buf bc
        SBAR();
        if (i + 3 < nk) stage(i + 3, bc);   // reuse just-freed buffer
        bc = (bc == 2) ? 0 : bc + 1;
    }

    #pragma unroll
    for (int mi = 0; mi < 4; ++mi)
        #pragma unroll
        for (int ni = 0; ni < 4; ++ni) {
            int ccol = cn + wn + ni * 16 + r;
            float bsv = bias ? bias[ccol] : 0.f;
            #pragma unroll
            for (int reg = 0; reg < 4; ++reg) {
                int row = bm + wm + mi * 16 + quad * 4 + reg;
                float v = acc[mi][ni][reg] + bsv;
                if (relu) v = fmaxf(v, 0.f);
                if (obf) ((u16*)Cb)[(size_t)row * ldc + ccol] = f2bf(v);
                else     ((float*)Cb)[(size_t)row * ldc + ccol] = v;
            }
        }
}

// ---------------- SRU scan: 1 wave/block, 4-buffer counted-vmcnt pipeline ----------------
#define TC 256
__global__ __launch_bounds__(64) void scan_k(const u16* __restrict__ Uf, const u16* __restrict__ Ub,
                                             const float* __restrict__ Xp, float* __restrict__ Xn,
                                             float* __restrict__ cstate, const float* __restrict__ vv,
                                             const float* __restrict__ bb, int t0f, int t0b, int init) {
    __shared__ __align__(16) char lds[4][10240];
    int tid = threadIdx.x;
    int d   = blockIdx.x >> 7;
    int idx = blockIdx.x & 127;
    int b   = idx >> 3;
    int h0  = (idx & 7) * 64;
    int h   = h0 + tid;
    int gid = d * 8192 + idx * 64 + tid;

    float v0 = vv[(d * 2 + 0) * 512 + h];
    float v1 = vv[(d * 2 + 1) * 512 + h];
    float b0 = bb[(d * 2 + 0) * 512 + h];
    float b1 = bb[(d * 2 + 1) * 512 + h];
    const u16* U = d ? Ub : Uf;
    int t0 = d ? t0b : t0f;
    float* ob = Xn + (size_t)b * 1024 + d * 512 + h;
    float cc = init ? 0.f : cstate[gid];
    int tstp = d ? -16384 : 16384;

    const char* gp[10];
    int dlt[10];
    #pragma unroll
    for (int it = 0; it < 10; ++it) {
        int u = it * 64 + tid;
        int s = u / 40;
        int j = u - s * 40;
        int sl0 = d ? (TC - 1 - s) : s;
        if (j < 24) {
            int k = j >> 3, jj = j & 7;
            gp[it] = (const char*)(U + ((size_t)(sl0 * 16 + b) * 1536 + k * 512 + h0 + jj * 8));
            dlt[it] = d ? -786432 : 786432;        // 16 slots * 16 rows * 1536 * 2B
        } else {
            gp[it] = (const char*)(Xp + ((size_t)(t0 + sl0) * 16384 + (size_t)b * 1024 + d * 512 + h0 + (j - 24) * 4));
            dlt[it] = d ? -1048576 : 1048576;      // 16 * 16384 * 4B
        }
    }
    char* lbase = (char*)&lds[0][0] + tid * 16;
    auto stage = [&](int bw) {
        char* lb = lbase + bw * 10240;
        #pragma unroll
        for (int it = 0; it < 10; ++it) {
            GLL(gp[it], lb + it * 1024);
            gp[it] += dlt[it];
        }
    };

    asm volatile("s_waitcnt vmcnt(0)" ::: "memory");   // drain param loads: counts start at 0
    SBAR();
    stage(0);
    stage(1);
    stage(2);
    SBAR();

    #pragma unroll 1
    for (int tk = 0; tk < 16; ++tk) {
        switch (tk) {
            case 0:  WAITVM(20); break;   // s1+s2
            case 1:  WAITVM(36); break;   // s2+c0+s3
            case 14: WAITVM(42); break;   // c12+s15+c13
            case 15: WAITVM(32); break;   // c13+c14
            default: WAITVM(52); break;   // c+s+c+s
        }
        SBAR();
        const char* Bb = (const char*)&lds[0][0] + (size_t)(tk & 3) * 10240;
        float* op = ob + (size_t)(t0 + (d ? (TC - 1 - tk * 16) : tk * 16)) * 16384;
        #pragma unroll
        for (int s = 0; s < 16; ++s) {
            const char* sb = Bb + s * 640;
            float u0 = bf2f(*(const u16*)(sb + tid * 2));
            float fp = bf2f(*(const u16*)(sb + 128 + tid * 2)) + b0;
            float rp = bf2f(*(const u16*)(sb + 256 + tid * 2)) + b1;
            float xr = *(const float*)(sb + 384 + tid * 4);
            float f = 1.f / (1.f + __expf(-(fp + v0 * cc)));
            float r = 1.f / (1.f + __expf(-(rp + v1 * cc)));
            cc = f * cc + (1.f - f) * u0;
            float th = 1.f - 2.f / (__expf(2.f * cc) + 1.f);
            *op = r * th + (1.f - r) * xr;
            op += tstp;
        }
        SBAR();
        if (tk < 13) stage((tk + 3) & 3);
        SBAR();
    }
    cstate[gid] = cc;
}

// ---------------- classifier head: 2 rows/block, k split 4-way, shuffle+LDS reduce ------
__global__ __launch_bounds__(256) void cls2_k(const float* __restrict__ FC1, const float* __restrict__ W2,
                                              const float* __restrict__ b2, void* __restrict__ out,
                                              const int* __restrict__ flag) {
    int isf32 = *flag;
    int tid = threadIdx.x;
    int rh = tid >> 7;              // row within block (0..1)
    int ks = (tid >> 5) & 3;        // k-segment (0..3), 128 k each
    int v  = tid & 31;              // output class lane
    int row = blockIdx.x * 2 + rh;
    const float* p = FC1 + (size_t)row * 512 + ks * 128;
    const float* wp = W2 + (size_t)ks * 128 * 29;
    float acc = 0.f;
    #pragma unroll 4
    for (int k = 0; k < 128; ++k) {
        float wv = (v < 29) ? wp[k * 29 + v] : 0.f;
        acc = fmaf(p[k], wv, acc);
    }
    acc += __shfl_xor(acc, 32);     // merge ks pairs within wave
    __shared__ float red[2][2][32];
    if ((tid & 63) < 32) red[rh][(tid >> 6) & 1][v] = acc;
    __syncthreads();
    if ((tid & 127) < 32 && v < 29) {
        float s = red[rh][0][v] + red[rh][1][v] + b2[v];
        int t = row >> 4, b = row & 15;
        size_t oi = ((size_t)b * 512 + t) * 29 + v;
        if (isf32) ((float*)out)[oi] = s;
        else       ((u16*)out)[oi]   = f2bf(s);
    }
}

// ---------------- launch ----------------
extern "C" void kernel_launch(void* const* d_in, const int* in_sizes, int n_in,
                              void* d_out, int out_size, void* d_ws, size_t ws_size,
                              hipStream_t stream) {
    const void* x      = d_in[0];
    const void* proj_w = d_in[11];
    const void* sru_w  = d_in[12];
    const void* cls_w1 = d_in[19];

    float* ws = (float*)d_ws;
    const size_t O_X    = 0;
    const size_t O_C    = 16777216;
    const size_t O_HA   = 25165824;
    const size_t O_SM   = 33850368;
    const size_t O_SR   = 34112512;
    const size_t O_CST  = 34374656;
    const size_t O_PARK = 34391040;
    const size_t O_FLAG = 34483488;
    const size_t TOTAL  = 34483504;   // 131.55 MiB
    if (ws_size < TOTAL * sizeof(float)) {
        fill_k<<<(out_size + 255) / 256, 256, 0, stream>>>((float*)d_out, out_size);
        return;
    }

    float* X   = ws + O_X;
    u16*   C   = (u16*)(ws + O_C);
    u16*   HA  = (u16*)(ws + O_HA);
    float* SM  = ws + O_SM;
    float* SR  = ws + O_SR;
    float* CST = ws + O_CST;
    float* PK  = ws + O_PARK;
    int*   FLG = (int*)(ws + O_FLAG);

    u16*   Abf = (u16*)(ws + O_C);
    u16*   BtP = (u16*)(ws + 0);
    float* XP0 = ws + 25165824;
    u16*   XL  = (u16*)(ws + 0);
    float* XP1 = ws + 4194304;
    u16*   Uf  = (u16*)(ws + 12582912);
    u16*   Ub  = (u16*)(ws + 15728640);
    u16*   BtS = (u16*)(ws + 18874368);
    u16*   BtC = (u16*)(ws + O_SM);
    float* FC1 = ws + 12582912;

    float* p_cnn_w = PK + 0;      float* p_cnn_b = PK + 288;
    float* p_rw1   = PK + 320;    float* p_rb1   = PK + 27968;
    float* p_rw2   = PK + 28064;  float* p_rb2   = PK + 55712;
    float* p_l1g   = PK + 55808;  float* p_l1b   = PK + 56000;
    float* p_l2g   = PK + 56192;  float* p_l2b   = PK + 56384;
    float* p_sv    = PK + 56576;  float* p_sb    = PK + 62720;
    float* p_slng  = PK + 68864;  float* p_slnb  = PK + 71936;
    float* p_clng  = PK + 75008;  float* p_clnb  = PK + 76032;
    float* p_cb1   = PK + 77056;  float* p_cw2   = PK + 77568;
    float* p_cb2   = PK + 92416;

    sniff_k<<<1, 256, 0, stream>>>((const u16*)x, FLG);

    CvtArgs ca;
    const int srcidx[19] = {1,2,3,4,5,6,7,8,9,10,13,14,15,16,17,18,20,21,22};
    const int lens[19]   = {288,32,27648,96,27648,96,192,192,192,192,6144,6144,3072,3072,1024,1024,512,14848,29};
    const int offs[19]   = {0,288,320,27968,28064,55712,55808,56000,56192,56384,56576,62720,68864,71936,75008,76032,77056,77568,92416};
    for (int i = 0; i < 19; ++i) { ca.src[i] = d_in[srcidx[i]]; ca.len[i] = lens[i]; ca.off[i] = offs[i]; }
    cvtall_k<<<dim3(108, 19), 256, 0, stream>>>(ca, PK, FLG);

    zero_k<<<2048, 256, 0, stream>>>((float4*)HA, 2171136);
    conv1_k<<<16384, 256, 0, stream>>>(x, p_cnn_w, p_cnn_b, X, FLG);

    stats_k<<<1024, 256, 0, stream>>>(X, 0, SM, SR);   // raw sums; apply_k finalizes inline
    for (int i = 0; i < 3; ++i) {
        apply_k<<<dim3(64, 16), 256, 0, stream>>>(X, 0, SM, SR, p_l1g + i * 64, p_l1b + i * 64, HA);
        zero_k<<<512, 256, 0, stream>>>((float4*)SM, 131072);   // SM+SR contiguous
        convm_k<<<dim3(4, 8, 16), 256, 0, stream>>>(HA, C, p_rw1 + i * 9216, p_rb1 + i * 32,
                                                    nullptr, SM, SR);
        apply_k<<<dim3(64, 16), 256, 0, stream>>>(C, 1, SM, SR, p_l2g + i * 64, p_l2b + i * 64, HA);
        if (i < 2) {
            zero_k<<<512, 256, 0, stream>>>((float4*)SM, 131072);
            convm_k<<<dim3(4, 8, 16), 256, 0, stream>>>(HA, X, p_rw2 + i * 9216, p_rb2 + i * 32,
                                                        X, SM, SR);
        } else {
            convm_k<<<dim3(4, 8, 16), 256, 0, stream>>>(HA, X, p_rw2 + i * 9216, p_rb2 + i * 32,
                                                        X, nullptr, nullptr);
        }
    }

    transpose_k<<<dim3(8, 32, 16), 256, 0, stream>>>(X, Abf);
    wtr_k<<<dim3(32, 16), 256, 0, stream>>>(proj_w, 1024, 0, BtP, 2048, FLG);
    gemm_bt<<<dim3(64, 8), 256, 0, stream>>>(Abf, Abf, 2048, BtP, 2048, XP0, XP0, 1024,
                                             1 << 30, nullptr, 0, 2048, 0);

    for (int l = 0; l < 3; ++l)
        wtr_k<<<dim3(16, 48), 256, 0, stream>>>(sru_w, 3072, (size_t)l * 3145728,
                                                BtS + (size_t)l * 3145728, 1024, FLG);
    wtr_k<<<dim3(16, 8), 256, 0, stream>>>(cls_w1, 512, 0, BtC, 1024, FLG);

    float* cur = XP0;
    float* nxt = XP1;
    for (int l = 0; l < 3; ++l) {
        lnlast_k<<<8192, 256, 0, stream>>>(cur, XL, p_slng + l * 1024, p_slnb + l * 1024, 1024);
        const u16* Btl = BtS + (size_t)l * 3145728;
        for (int j = 0; j < 2; ++j) {
            int t0f = j * TC;
            int t0b = (1 - j) * TC;
            gemm_bt<<<dim3(32, 24), 256, 0, stream>>>(XL + (size_t)t0f * 16 * 1024,
                                                      XL + (size_t)t0b * 16 * 1024, 1024,
                                                      Btl, 1024, Uf, Ub, 1536, 1536,
                                                      nullptr, 0, 1024, 1);
            scan_k<<<256, 64, 0, stream>>>(Uf, Ub, cur, nxt, CST,
                                           p_sv + l * 2048, p_sb + l * 2048, t0f, t0b, j == 0);
        }
        float* tmp = cur; cur = nxt; nxt = tmp;
    }

    lnlast_k<<<8192, 256, 0, stream>>>(cur, XL, p_clng, p_clnb, 1024);
    gemm_bt<<<dim3(64, 4), 256, 0, stream>>>(XL, XL, 1024, BtC, 1024, FC1, FC1, 512,
                                             1 << 30, p_cb1, 1, 1024, 0);
    cls2_k<<<4096, 256, 0, stream>>>(FC1, p_cw2, p_cb2, d_out, FLG);
}